// Round 2
// baseline (432.504 us; speedup 1.0000x reference)
//
#include <hip/hip_runtime.h>
#include <cmath>

#define N_TOK 8192
#define DIM   384
#define NEXP  8
#define HID   1536
#define OUTD  384
#define CAP_MT 72        // 32-row gather tiles per expert (2304 tokens, mean 2048 + 6 sigma)
#define CAP_TOK 2304
#define CAP_TB 18        // 128-row expert blocks per expert
#define HPITCH 136       // h_lds row pitch in shorts (272B): 16B-aligned, measured 0 conflicts

typedef __attribute__((ext_vector_type(8)))  __bf16 bf16x8;
typedef __attribute__((ext_vector_type(16))) float  f32x16;
typedef __attribute__((ext_vector_type(4)))  float  f32x4;          // nontemporal builtins
typedef __attribute__((ext_vector_type(8)))  unsigned short u16x8;  // nontemporal bf16 loads

__device__ __forceinline__ unsigned short f2bf(float f) {
    unsigned u = __float_as_uint(f);
    u += 0x7FFF + ((u >> 16) & 1);          // round-to-nearest-even
    return (unsigned short)(u >> 16);
}

__device__ __forceinline__ float bf2f(unsigned short s) {
    return __uint_as_float(((unsigned)s) << 16);
}

__device__ __forceinline__ float gelu_exact(float x) {
    return 0.5f * x * (1.0f + erff(x * 0.70710678118654752f));
}

// async global->LDS, 16B per lane; LDS dest = wave-uniform tile base (HW adds lane*16)
__device__ __forceinline__ void cp16(const unsigned short* g, unsigned short* l) {
    __builtin_amdgcn_global_load_lds(
        (const __attribute__((address_space(1))) unsigned int*)g,
        (__attribute__((address_space(3))) unsigned int*)l, 16, 0, 0);
}

// ------------------------------------------------- W[e][K][N] fp32 -> B-fragment order bf16
// dst[((e*NT + nt)*KT + kt)*64 + l][j] = bf16(src[e][kt*16 + (l>>5)*8 + j][nt*32 + (l&31)])
// Also zeroes cnt from block 0 when cnt != nullptr (saves a launch).
__global__ void swizzle_kernel(const float* __restrict__ src, unsigned short* __restrict__ dst,
                               int K, int N, int NT, int KT, int* __restrict__ cnt) {
    if (cnt && blockIdx.x == 0 && threadIdx.x < NEXP) cnt[threadIdx.x] = 0;
    int gid = blockIdx.x * blockDim.x + threadIdx.x;
    int total = NEXP * NT * KT * 64;
    if (gid >= total) return;
    int l  = gid & 63;
    int kt = (gid >> 6) % KT;
    int nt = ((gid >> 6) / KT) % NT;
    int e  = gid / (64 * KT * NT);
    const float* s = src + ((size_t)e * K + kt * 16 + (l >> 5) * 8) * N + nt * 32 + (l & 31);
    unsigned short r[8];
    #pragma unroll
    for (int j = 0; j < 8; ++j) r[j] = f2bf(s[(size_t)j * N]);
    *(uint4*)(dst + (size_t)gid * 8) = *(uint4*)r;
}

// ---------------------------------------------------------------- router
__global__ void router_kernel(const float* __restrict__ x, const float* __restrict__ Wg,
                              const float* __restrict__ bg, int* __restrict__ cnt,
                              int* __restrict__ btok, int* __restrict__ tokmap,
                              float* __restrict__ gmap) {
    __shared__ float WgL[DIM * NEXP];
    __shared__ int lcnt[NEXP];
    __shared__ int lbase[NEXP];
    int tid = threadIdx.x;
    for (int i = tid; i < DIM * NEXP; i += 256) WgL[i] = Wg[i];
    if (tid < NEXP) lcnt[tid] = 0;
    __syncthreads();

    int t = blockIdx.x * 256 + tid;
    float lg[NEXP];
    #pragma unroll
    for (int e = 0; e < NEXP; ++e) lg[e] = bg[e];

    const float4* xr = (const float4*)(x + (size_t)t * DIM);
    for (int d4 = 0; d4 < DIM / 4; ++d4) {
        float4 v = xr[d4];
        const float* wrow = &WgL[d4 * 4 * NEXP];
        #pragma unroll
        for (int e = 0; e < NEXP; ++e)
            lg[e] += v.x * wrow[e] + v.y * wrow[NEXP + e]
                   + v.z * wrow[2 * NEXP + e] + v.w * wrow[3 * NEXP + e];
    }

    float v0 = -INFINITY, v1 = -INFINITY; int i0 = 0, i1 = 0;
    #pragma unroll
    for (int e = 0; e < NEXP; ++e) {
        float v = lg[e];
        if (v > v0)      { v1 = v0; i1 = i0; v0 = v; i0 = e; }
        else if (v > v1) { v1 = v;  i1 = e; }
    }
    float e1 = expf(v1 - v0);
    float g0 = 1.f / (1.f + e1);
    float g1 = e1  / (1.f + e1);

    int p0 = atomicAdd(&lcnt[i0], 1);
    int p1 = atomicAdd(&lcnt[i1], 1);
    __syncthreads();
    if (tid < NEXP) lbase[tid] = atomicAdd(&cnt[tid], lcnt[tid]);
    __syncthreads();
    int o0 = lbase[i0] + p0, o1 = lbase[i1] + p1;
    btok[i0 * N_TOK + o0] = t;
    btok[i1 * N_TOK + o1] = t;
    ((int4*)tokmap)[t] = make_int4(i0, o0, i1, o1);
    ((float2*)gmap)[t] = make_float2(g0, g1);
}

// ------------------------------------------ gather x rows into A-fragment order (bf16)
__global__ void gather_kernel(const float* __restrict__ x, const int* __restrict__ cnt,
                              const int* __restrict__ btok, unsigned short* __restrict__ xg) {
    int mt = blockIdx.x, e = blockIdx.y;
    int cntE = cnt[e];
    if (mt * 32 >= cntE) return;
    int tid = threadIdx.x;                 // 256
    int m = tid & 31, kt0 = tid >> 5;      // 32 x 8
    int pos = mt * 32 + m;
    int idx = (pos < cntE) ? pos : cntE - 1;   // clamp pad rows (masked later)
    int tok = btok[e * N_TOK + idx];
    const float* xr = x + (size_t)tok * DIM;
    #pragma unroll
    for (int kk = 0; kk < 3; ++kk) {
        int kt = kt0 + kk * 8;
        #pragma unroll
        for (int kh = 0; kh < 2; ++kh) {
            float4 v0 = *(const float4*)(xr + kt * 16 + kh * 8);
            float4 v1 = *(const float4*)(xr + kt * 16 + kh * 8 + 4);
            unsigned short rr[8];
            rr[0] = f2bf(v0.x); rr[1] = f2bf(v0.y); rr[2] = f2bf(v0.z); rr[3] = f2bf(v0.w);
            rr[4] = f2bf(v1.x); rr[5] = f2bf(v1.y); rr[6] = f2bf(v1.z); rr[7] = f2bf(v1.w);
            *(uint4*)(xg + (size_t)(((e * CAP_MT + mt) * 24 + kt) * 64 + kh * 32 + m) * 8) =
                *(uint4*)rr;
        }
    }
}

// ---------------------------------------------------------------- fused expert MLP
// 512 thr (8 waves). Block = (e = L&7 [XCD-pin], hs quarter of HID, tb: 128 tokens).
// T3+T4 pipeline: 36 uniform stages of 24 tiles (24 KB), 3 global_load_lds per wave per
// stage; 4 stage buffers, depth-3 issue-ahead. Per stage: counted s_waitcnt vmcnt(6)
// (stage-s loads landed, 6 stay in flight — NEVER drain to 0 in the loop) -> raw
// s_barrier -> issue stage s+3 (its buffer was consumed at stage s-1; the barrier just
// crossed proves all waves are past that) -> consume. One barrier per stage.
// Fully unrolled so buffer indices are compile-time (distinct LDS ranges -> no
// compiler-inserted conservative drains). LDS 130 KB -> 1 block/CU (8-phase regime).
__global__ __launch_bounds__(512, 2) void expert_kernel(
        const unsigned short* __restrict__ xg,  const unsigned short* __restrict__ w1s,
        const unsigned short* __restrict__ w2s, const float* __restrict__ b1,
        const int* __restrict__ cnt,            unsigned short* __restrict__ yp4) {
    int L  = blockIdx.x;
    int e  = L & 7;
    int r  = L >> 3;
    int hs = r & 3;               // hid-slice (384 cols)
    int tb = r >> 2;              // 128-token block
    int cntE = cnt[e];
    if (tb * 128 >= cntE) return;

    __shared__ unsigned short stg[4][12288];         // 4 x 24 KB stage buffers (24 x 1KB tiles)
    __shared__ unsigned short h_lds[128 * HPITCH];   // 34.8 KB -> total 130.8 KB, 1 block/CU

    int tid  = threadIdx.x;
    int wave = tid >> 6, lane = tid & 63;
    int m31 = lane & 31, kh = lane >> 5;
    int mh = wave >> 2, ni = wave & 3;    // GEMM1: mh = row-half (64 rows), ni = 32-col tile
    int oj = ni;                          // GEMM2: oj = 96-col out group, same mh

    f32x16 acc2[6];
    #pragma unroll
    for (int i = 0; i < 6; ++i)
        acc2[i] = (f32x16){0.f,0.f,0.f,0.f,0.f,0.f,0.f,0.f,0.f,0.f,0.f,0.f,0.f,0.f,0.f,0.f};
    f32x16 acc1[2];

    const unsigned short* xg_e = xg + ((size_t)(e * CAP_MT + tb * 4) * 24) * 512;
    const unsigned short* w1_e = w1s + ((size_t)(e * 48 + hs * 12) * 24) * 512;

    // issue pipeline stage t (t in [0,36)): 3 cp16 per wave into stg[t&3].
    // G1 stage (ph<8): tiles [0..11] = x (mt*3+ktl), [12..23] = W1 (nn*3+ktl); wave<4
    // loads x with mt=wave, else W1 with nn=wave-4 (tl = wave*3+q matches layout).
    // G2 stage: tiles [nc*2+j], tl = wave*3+q -> nc=tl>>1, j=tl&1.
    auto issue = [&](int t) {
        if (t >= 36) return;
        int hcx = t / 12, ph = t - (t / 12) * 12;
        unsigned short* dst = &stg[t & 3][0];
        if (ph < 8) {
            #pragma unroll
            for (int q = 0; q < 3; ++q) {
                const unsigned short* src = (wave < 4)
                    ? xg_e + ((size_t)wave * 24 + ph * 3 + q) * 512
                    : w1_e + ((size_t)(hcx * 4 + (wave - 4)) * 24 + ph * 3 + q) * 512;
                cp16(src + lane * 8, dst + (wave * 3 + q) * 512);
            }
        } else {
            int sg = ph - 8;
            #pragma unroll
            for (int q = 0; q < 3; ++q) {
                int tl = wave * 3 + q;
                int nc = tl >> 1, j = tl & 1;
                const unsigned short* src =
                    w2s + ((size_t)(e * 12 + nc) * 96 + hs * 24 + hcx * 8 + sg * 2 + j) * 512;
                cp16(src + lane * 8, dst + tl * 512);
            }
        }
    };

    issue(0); issue(1); issue(2);                    // prologue: 9 loads in flight

    #pragma unroll
    for (int s = 0; s < 36; ++s) {
        const int hc = s / 12, ph = s - (s / 12) * 12, buf = s & 3;
        // ---- stage-s data ready: wait ONLY the oldest 3 loads; keep 6 in flight.
        // lgkmcnt(0) additionally makes this wave's h_lds ds_writes barrier-visible.
        if (s <= 33)      asm volatile("s_waitcnt vmcnt(6) lgkmcnt(0)" ::: "memory");
        else if (s == 34) asm volatile("s_waitcnt vmcnt(3) lgkmcnt(0)" ::: "memory");
        else              asm volatile("s_waitcnt vmcnt(0) lgkmcnt(0)" ::: "memory");
        __builtin_amdgcn_sched_barrier(0);
        __builtin_amdgcn_s_barrier();
        __builtin_amdgcn_sched_barrier(0);
        issue(s + 3);                                // overwrites buf consumed at stage s-1

        if (ph < 8) {
            // ============ GEMM1 consume: 3 kt, 6 MFMA ============
            if (ph == 0) {
                acc1[0] = (f32x16){0.f,0.f,0.f,0.f,0.f,0.f,0.f,0.f,0.f,0.f,0.f,0.f,0.f,0.f,0.f,0.f};
                acc1[1] = acc1[0];
            }
            #pragma unroll
            for (int kt = 0; kt < 3; ++kt) {
                bf16x8 b  = *(const bf16x8*)&stg[buf][(12 + ni * 3 + kt) * 512 + lane * 8];
                bf16x8 a0 = *(const bf16x8*)&stg[buf][((mh * 2 + 0) * 3 + kt) * 512 + lane * 8];
                bf16x8 a1 = *(const bf16x8*)&stg[buf][((mh * 2 + 1) * 3 + kt) * 512 + lane * 8];
                acc1[0] = __builtin_amdgcn_mfma_f32_32x32x16_bf16(a0, b, acc1[0], 0, 0, 0);
                acc1[1] = __builtin_amdgcn_mfma_f32_32x32x16_bf16(a1, b, acc1[1], 0, 0, 0);
            }
            if (ph == 7) {
                // ---- bias + exact gelu -> h_lds; visible after next stage's barrier
                int colL = ni * 32 + m31;
                float b1v = b1[e * HID + hs * 384 + hc * 128 + colL];
                #pragma unroll
                for (int ss2 = 0; ss2 < 2; ++ss2)
                    #pragma unroll
                    for (int rr = 0; rr < 16; ++rr) {
                        int row = mh * 64 + ss2 * 32 + (rr & 3) + 8 * (rr >> 2) + 4 * kh;
                        h_lds[row * HPITCH + colL] = f2bf(gelu_exact(acc1[ss2][rr] + b1v));
                    }
            }
        } else {
            // ============ GEMM2 consume: 2 ks, 12 MFMA ============
            int sg = ph - 8;
            #pragma unroll
            for (int j = 0; j < 2; ++j) {
                int kcol = (sg * 2 + j) * 16 + kh * 8;
                bf16x8 a0 = *(const bf16x8*)&h_lds[(mh * 64 +  0 + m31) * HPITCH + kcol];
                bf16x8 a1 = *(const bf16x8*)&h_lds[(mh * 64 + 32 + m31) * HPITCH + kcol];
                #pragma unroll
                for (int o = 0; o < 3; ++o) {
                    bf16x8 b = *(const bf16x8*)&stg[buf][((oj * 3 + o) * 2 + j) * 512 + lane * 8];
                    acc2[o * 2 + 0] = __builtin_amdgcn_mfma_f32_32x32x16_bf16(a0, b, acc2[o * 2 + 0], 0, 0, 0);
                    acc2[o * 2 + 1] = __builtin_amdgcn_mfma_f32_32x32x16_bf16(a1, b, acc2[o * 2 + 1], 0, 0, 0);
                }
            }
        }
    }

    // ---- epilogue: plain bf16 stores to private partial slice (64B lines, L2-buffered)
    unsigned short* ypb = yp4 + ((size_t)(hs * NEXP + e) * CAP_TOK) * OUTD;
    #pragma unroll
    for (int o = 0; o < 3; ++o) {
        int col = (oj * 3 + o) * 32 + m31;
        #pragma unroll
        for (int ss2 = 0; ss2 < 2; ++ss2)
            #pragma unroll
            for (int rr = 0; rr < 16; ++rr) {
                int row = mh * 64 + ss2 * 32 + (rr & 3) + 8 * (rr >> 2) + 4 * kh;
                int pos = tb * 128 + row;
                if (pos < cntE)
                    ypb[(size_t)pos * OUTD + col] = f2bf(acc2[o * 2 + ss2][rr]);
            }
    }
}

// ----------- reduce: out = sum_k g_k * (sum_hs yp4[hs][e_k][pos_k] + b2[e_k]); bf16 partials
__global__ void reduce_kernel(const unsigned short* __restrict__ yp4,
                              const int* __restrict__ tokmap, const float* __restrict__ gmap,
                              const float* __restrict__ b2, float* __restrict__ out) {
    int gid = blockIdx.x * 256 + threadIdx.x;      // N_TOK * 48 threads
    int t = gid / 48, q = gid - t * 48;            // q: 8-col group
    int4   tm = ((const int4*)tokmap)[t];
    float2 g  = ((const float2*)gmap)[t];
    const size_t hstep = (size_t)NEXP * CAP_TOK * OUTD;
    const unsigned short* p0 = yp4 + ((size_t)tm.x * CAP_TOK + tm.y) * OUTD + q * 8;
    const unsigned short* p1 = yp4 + ((size_t)tm.z * CAP_TOK + tm.w) * OUTD + q * 8;
    float y0[8] = {0,0,0,0,0,0,0,0};
    float y1[8] = {0,0,0,0,0,0,0,0};
    #pragma unroll
    for (int h = 0; h < 4; ++h) {
        u16x8 a = __builtin_nontemporal_load((const u16x8*)(p0 + h * hstep));
        u16x8 b = __builtin_nontemporal_load((const u16x8*)(p1 + h * hstep));
        #pragma unroll
        for (int j = 0; j < 8; ++j) { y0[j] += bf2f(a[j]); y1[j] += bf2f(b[j]); }
    }
    const float* c0 = &b2[tm.x * OUTD + q * 8];
    const float* c1 = &b2[tm.z * OUTD + q * 8];
    f32x4 r0, r1;
    #pragma unroll
    for (int j = 0; j < 4; ++j) {
        r0[j] = g.x * (y0[j] + c0[j]) + g.y * (y1[j] + c1[j]);
        r1[j] = g.x * (y0[4 + j] + c0[4 + j]) + g.y * (y1[4 + j] + c1[4 + j]);
    }
    float* op = &out[(size_t)t * OUTD + q * 8];
    __builtin_nontemporal_store(r0, (f32x4*)op);
    __builtin_nontemporal_store(r1, (f32x4*)(op + 4));
}

// ---------------------------------------------------------------- launch
extern "C" void kernel_launch(void* const* d_in, const int* in_sizes, int n_in,
                              void* d_out, int out_size, void* d_ws, size_t ws_size,
                              hipStream_t stream) {
    const float* x  = (const float*)d_in[0];
    const float* Wg = (const float*)d_in[1];
    const float* bg = (const float*)d_in[2];
    const float* W1 = (const float*)d_in[3];
    const float* b1 = (const float*)d_in[4];
    const float* W2 = (const float*)d_in[5];
    const float* b2 = (const float*)d_in[6];
    float* out = (float*)d_out;

    char* ws = (char*)d_ws;                                    // all offsets 1KB-aligned
    int*            cnt    = (int*)ws;                         // 32 B
    int*            btok   = (int*)(ws + 1024);                // 256 KB
    int*            tokmap = (int*)(ws + 263168);              // 128 KB
    float*          gmap   = (float*)(ws + 394240);            // 64 KB
    unsigned short* xg     = (unsigned short*)(ws + 459776);   // 13.5 MB
    unsigned short* w1s    = (unsigned short*)(ws + 14615552); // 9.44 MB
    unsigned short* w2s    = (unsigned short*)(ws + 24052736); // 9.44 MB
    unsigned short* yp4    = (unsigned short*)(ws + 33489920); // 56.6 MB -> end ~90 MB

    // W1: K=DIM, N=HID -> NT=48, KT=24 ; W2: K=HID, N=OUTD -> NT=12, KT=96
    hipLaunchKernelGGL(swizzle_kernel, dim3(NEXP * 48 * 24 * 64 / 256), dim3(256), 0, stream,
                       W1, w1s, DIM, HID, 48, 24, cnt);
    hipLaunchKernelGGL(swizzle_kernel, dim3(NEXP * 12 * 96 * 64 / 256), dim3(256), 0, stream,
                       W2, w2s, HID, OUTD, 12, 96, (int*)nullptr);
    hipLaunchKernelGGL(router_kernel, dim3(N_TOK / 256), dim3(256), 0, stream,
                       x, Wg, bg, cnt, btok, tokmap, gmap);
    hipLaunchKernelGGL(gather_kernel, dim3(CAP_MT, NEXP), dim3(256), 0, stream,
                       x, cnt, btok, xg);
    hipLaunchKernelGGL(expert_kernel, dim3(NEXP * 4 * CAP_TB), dim3(512), 0, stream,
                       xg, w1s, w2s, b1, cnt, yp4);
    hipLaunchKernelGGL(reduce_kernel, dim3(N_TOK * 48 / 256), dim3(256), 0, stream,
                       yp4, tokmap, gmap, b2, out);
}

// Round 3
// 310.826 us; speedup vs baseline: 1.3915x; 1.3915x over previous
//
#include <hip/hip_runtime.h>
#include <cmath>

#define N_TOK 8192
#define DIM   384
#define NEXP  8
#define HID   1536
#define OUTD  384
#define CAP_MT 72        // 32-row gather tiles per expert (2304 tokens, mean 2048 + 6 sigma)
#define CAP_TOK 2304
#define CAP_TB 18        // 128-row expert blocks per expert
#define HPITCH 136       // h_lds row pitch in shorts (272B): 16B-aligned, measured 0 conflicts

typedef __attribute__((ext_vector_type(8)))  __bf16 bf16x8;
typedef __attribute__((ext_vector_type(16))) float  f32x16;
typedef __attribute__((ext_vector_type(4)))  float  f32x4;          // nontemporal builtins
typedef __attribute__((ext_vector_type(8)))  unsigned short u16x8;  // nontemporal bf16 loads

__device__ __forceinline__ unsigned short f2bf(float f) {
    unsigned u = __float_as_uint(f);
    u += 0x7FFF + ((u >> 16) & 1);          // round-to-nearest-even
    return (unsigned short)(u >> 16);
}

__device__ __forceinline__ float bf2f(unsigned short s) {
    return __uint_as_float(((unsigned)s) << 16);
}

__device__ __forceinline__ float gelu_exact(float x) {
    return 0.5f * x * (1.0f + erff(x * 0.70710678118654752f));
}

// async global->LDS, 16B per lane; LDS dest = wave-uniform tile base (HW adds lane*16)
__device__ __forceinline__ void cp16(const unsigned short* g, unsigned short* l) {
    __builtin_amdgcn_global_load_lds(
        (const __attribute__((address_space(1))) unsigned int*)g,
        (__attribute__((address_space(3))) unsigned int*)l, 16, 0, 0);
}

// ------------------------------------------------- W[e][K][N] fp32 -> B-fragment order bf16
// dst[((e*NT + nt)*KT + kt)*64 + l][j] = bf16(src[e][kt*16 + (l>>5)*8 + j][nt*32 + (l&31)])
// Also zeroes cnt from block 0 when cnt != nullptr (saves a launch).
__global__ void swizzle_kernel(const float* __restrict__ src, unsigned short* __restrict__ dst,
                               int K, int N, int NT, int KT, int* __restrict__ cnt) {
    if (cnt && blockIdx.x == 0 && threadIdx.x < NEXP) cnt[threadIdx.x] = 0;
    int gid = blockIdx.x * blockDim.x + threadIdx.x;
    int total = NEXP * NT * KT * 64;
    if (gid >= total) return;
    int l  = gid & 63;
    int kt = (gid >> 6) % KT;
    int nt = ((gid >> 6) / KT) % NT;
    int e  = gid / (64 * KT * NT);
    const float* s = src + ((size_t)e * K + kt * 16 + (l >> 5) * 8) * N + nt * 32 + (l & 31);
    unsigned short r[8];
    #pragma unroll
    for (int j = 0; j < 8; ++j) r[j] = f2bf(s[(size_t)j * N]);
    *(uint4*)(dst + (size_t)gid * 8) = *(uint4*)r;
}

// ---------------------------------------------------------------- router
__global__ void router_kernel(const float* __restrict__ x, const float* __restrict__ Wg,
                              const float* __restrict__ bg, int* __restrict__ cnt,
                              int* __restrict__ btok, int* __restrict__ tokmap,
                              float* __restrict__ gmap) {
    __shared__ float WgL[DIM * NEXP];
    __shared__ int lcnt[NEXP];
    __shared__ int lbase[NEXP];
    int tid = threadIdx.x;
    for (int i = tid; i < DIM * NEXP; i += 256) WgL[i] = Wg[i];
    if (tid < NEXP) lcnt[tid] = 0;
    __syncthreads();

    int t = blockIdx.x * 256 + tid;
    float lg[NEXP];
    #pragma unroll
    for (int e = 0; e < NEXP; ++e) lg[e] = bg[e];

    const float4* xr = (const float4*)(x + (size_t)t * DIM);
    for (int d4 = 0; d4 < DIM / 4; ++d4) {
        float4 v = xr[d4];
        const float* wrow = &WgL[d4 * 4 * NEXP];
        #pragma unroll
        for (int e = 0; e < NEXP; ++e)
            lg[e] += v.x * wrow[e] + v.y * wrow[NEXP + e]
                   + v.z * wrow[2 * NEXP + e] + v.w * wrow[3 * NEXP + e];
    }

    float v0 = -INFINITY, v1 = -INFINITY; int i0 = 0, i1 = 0;
    #pragma unroll
    for (int e = 0; e < NEXP; ++e) {
        float v = lg[e];
        if (v > v0)      { v1 = v0; i1 = i0; v0 = v; i0 = e; }
        else if (v > v1) { v1 = v;  i1 = e; }
    }
    float e1 = expf(v1 - v0);
    float g0 = 1.f / (1.f + e1);
    float g1 = e1  / (1.f + e1);

    int p0 = atomicAdd(&lcnt[i0], 1);
    int p1 = atomicAdd(&lcnt[i1], 1);
    __syncthreads();
    if (tid < NEXP) lbase[tid] = atomicAdd(&cnt[tid], lcnt[tid]);
    __syncthreads();
    int o0 = lbase[i0] + p0, o1 = lbase[i1] + p1;
    btok[i0 * N_TOK + o0] = t;
    btok[i1 * N_TOK + o1] = t;
    ((int4*)tokmap)[t] = make_int4(i0, o0, i1, o1);
    ((float2*)gmap)[t] = make_float2(g0, g1);
}

// ------------------------------------------ gather x rows into A-fragment order (bf16)
__global__ void gather_kernel(const float* __restrict__ x, const int* __restrict__ cnt,
                              const int* __restrict__ btok, unsigned short* __restrict__ xg) {
    int mt = blockIdx.x, e = blockIdx.y;
    int cntE = cnt[e];
    if (mt * 32 >= cntE) return;
    int tid = threadIdx.x;                 // 256
    int m = tid & 31, kt0 = tid >> 5;      // 32 x 8
    int pos = mt * 32 + m;
    int idx = (pos < cntE) ? pos : cntE - 1;   // clamp pad rows (masked later)
    int tok = btok[e * N_TOK + idx];
    const float* xr = x + (size_t)tok * DIM;
    #pragma unroll
    for (int kk = 0; kk < 3; ++kk) {
        int kt = kt0 + kk * 8;
        #pragma unroll
        for (int kh = 0; kh < 2; ++kh) {
            float4 v0 = *(const float4*)(xr + kt * 16 + kh * 8);
            float4 v1 = *(const float4*)(xr + kt * 16 + kh * 8 + 4);
            unsigned short rr[8];
            rr[0] = f2bf(v0.x); rr[1] = f2bf(v0.y); rr[2] = f2bf(v0.z); rr[3] = f2bf(v0.w);
            rr[4] = f2bf(v1.x); rr[5] = f2bf(v1.y); rr[6] = f2bf(v1.z); rr[7] = f2bf(v1.w);
            *(uint4*)(xg + (size_t)(((e * CAP_MT + mt) * 24 + kt) * 64 + kh * 32 + m) * 8) =
                *(uint4*)rr;
        }
    }
}

// ---------------------------------------------------------------- fused expert MLP
// 512 thr (8 waves). Block = (e = L&7 [XCD-pin], hs quarter of HID, tb: 128 tokens).
// T3+T4 pipeline, ROLLED (R2's full unroll spilled to scratch: FETCH/WRITE doubled).
// 36 uniform stages of 24 tiles (24 KB), exactly 3 global_load_lds per wave per stage;
// 3 stage buffers, depth-2 issue-ahead. Per stage:
//   issue(s+2) -> s_waitcnt vmcnt(6) lgkmcnt(0)  (oldest 3 landed, 6 stay in flight,
//   NEVER drained to 0 in the loop) -> s_barrier -> consume -> lgkmcnt(0)+s_barrier
//   (consume + h_lds writes complete before buffer/h reuse).
// Occupancy note: acc1+acc2 = 128 AGPRs + ~112 VGPRs = 1 block/CU regardless of LDS
// (R0/R2 occupancy both ~15-17%), so 108.5 KB LDS costs nothing.
// b1 values are hoisted to the prologue: an in-loop global load would force the
// compiler to emit vmcnt(0) for its result, draining the pipeline at every ph==7.
__global__ __launch_bounds__(512, 2) void expert_kernel(
        const unsigned short* __restrict__ xg,  const unsigned short* __restrict__ w1s,
        const unsigned short* __restrict__ w2s, const float* __restrict__ b1,
        const int* __restrict__ cnt,            unsigned short* __restrict__ yp4) {
    int L  = blockIdx.x;
    int e  = L & 7;
    int r  = L >> 3;
    int hs = r & 3;               // hid-slice (384 cols)
    int tb = r >> 2;              // 128-token block
    int cntE = cnt[e];
    if (tb * 128 >= cntE) return;

    __shared__ unsigned short stg[3][12288];         // 3 x 24 KB stage buffers (24 x 1KB tiles)
    __shared__ unsigned short h_lds[128 * HPITCH];   // 34.8 KB -> total 108.5 KB, 1 block/CU

    int tid  = threadIdx.x;
    int wave = tid >> 6, lane = tid & 63;
    int m31 = lane & 31, kh = lane >> 5;
    int mh = wave >> 2, ni = wave & 3;    // GEMM1: mh = row-half (64 rows), ni = 32-col tile
    int oj = ni;                          // GEMM2: oj = 96-col out group, same mh

    f32x16 acc2[6];
    #pragma unroll
    for (int i = 0; i < 6; ++i)
        acc2[i] = (f32x16){0.f,0.f,0.f,0.f,0.f,0.f,0.f,0.f,0.f,0.f,0.f,0.f,0.f,0.f,0.f,0.f};
    f32x16 acc1[2];

    const unsigned short* xg_e = xg + ((size_t)(e * CAP_MT + tb * 4) * 24) * 512;
    const unsigned short* w1_e = w1s + ((size_t)(e * 48 + hs * 12) * 24) * 512;

    // prologue: hoist the 3 per-hc bias values (no global loads inside the K-loop!)
    int colL = ni * 32 + m31;
    const float* b1p = b1 + e * HID + hs * 384 + colL;
    float b1v0 = b1p[0], b1v1 = b1p[128], b1v2 = b1p[256];

    // issue pipeline stage t (t in [0,36)): 3 cp16 per wave into stg[t % 3].
    // G1 stage (ph<8): tiles [0..11] = x (mt*3+ktl), [12..23] = W1 (nn*3+ktl); wave<4
    // loads x with mt=wave, else W1 with nn=wave-4 (tl = wave*3+q matches layout).
    // G2 stage: tiles [nc*2+j], tl = wave*3+q -> nc=tl>>1, j=tl&1.
    auto issue = [&](int t) {
        if (t >= 36) return;
        int hcx = t / 12, ph = t - hcx * 12;
        unsigned short* dst = &stg[t % 3][0];
        if (ph < 8) {
            #pragma unroll
            for (int q = 0; q < 3; ++q) {
                const unsigned short* src = (wave < 4)
                    ? xg_e + ((size_t)wave * 24 + ph * 3 + q) * 512
                    : w1_e + ((size_t)(hcx * 4 + (wave - 4)) * 24 + ph * 3 + q) * 512;
                cp16(src + lane * 8, dst + (wave * 3 + q) * 512);
            }
        } else {
            int sg = ph - 8;
            #pragma unroll
            for (int q = 0; q < 3; ++q) {
                int tl = wave * 3 + q;
                int nc = tl >> 1, j = tl & 1;
                const unsigned short* src =
                    w2s + ((size_t)(e * 12 + nc) * 96 + hs * 24 + hcx * 8 + sg * 2 + j) * 512;
                cp16(src + lane * 8, dst + tl * 512);
            }
        }
    };

    issue(0); issue(1);                              // prologue: 6 loads in flight

    for (int s = 0; s < 36; ++s) {                   // ROLLED — do not unroll
        const int hc = s / 12, ph = s - hc * 12, buf = s % 3;
        issue(s + 2);                                // buf (s+2)%3 was consumed at s-1;
                                                     // barrier-2 of s-1 makes this safe
        // wait ONLY the oldest 3 loads (stage s); 6 younger stay in flight.
        if (s < 34)       asm volatile("s_waitcnt vmcnt(6) lgkmcnt(0)" ::: "memory");
        else if (s == 34) asm volatile("s_waitcnt vmcnt(3) lgkmcnt(0)" ::: "memory");
        else              asm volatile("s_waitcnt vmcnt(0) lgkmcnt(0)" ::: "memory");
        __builtin_amdgcn_sched_barrier(0);
        __builtin_amdgcn_s_barrier();                // barrier-1: stage-s tiles visible
        __builtin_amdgcn_sched_barrier(0);

        if (ph < 8) {
            // ============ GEMM1 consume: 3 kt, 6 MFMA ============
            if (ph == 0) {
                acc1[0] = (f32x16){0.f,0.f,0.f,0.f,0.f,0.f,0.f,0.f,0.f,0.f,0.f,0.f,0.f,0.f,0.f,0.f};
                acc1[1] = acc1[0];
            }
            #pragma unroll
            for (int kt = 0; kt < 3; ++kt) {
                bf16x8 b  = *(const bf16x8*)&stg[buf][(12 + ni * 3 + kt) * 512 + lane * 8];
                bf16x8 a0 = *(const bf16x8*)&stg[buf][((mh * 2 + 0) * 3 + kt) * 512 + lane * 8];
                bf16x8 a1 = *(const bf16x8*)&stg[buf][((mh * 2 + 1) * 3 + kt) * 512 + lane * 8];
                acc1[0] = __builtin_amdgcn_mfma_f32_32x32x16_bf16(a0, b, acc1[0], 0, 0, 0);
                acc1[1] = __builtin_amdgcn_mfma_f32_32x32x16_bf16(a1, b, acc1[1], 0, 0, 0);
            }
            if (ph == 7) {
                // ---- bias + exact gelu -> h_lds; lgkm-drained before barrier-2 below,
                //      so all waves see h at the next stage's barrier-1.
                float b1v = (hc == 0) ? b1v0 : (hc == 1) ? b1v1 : b1v2;
                #pragma unroll
                for (int ss2 = 0; ss2 < 2; ++ss2)
                    #pragma unroll
                    for (int rr = 0; rr < 16; ++rr) {
                        int row = mh * 64 + ss2 * 32 + (rr & 3) + 8 * (rr >> 2) + 4 * kh;
                        h_lds[row * HPITCH + colL] = f2bf(gelu_exact(acc1[ss2][rr] + b1v));
                    }
            }
        } else {
            // ============ GEMM2 consume: 2 ks, 12 MFMA ============
            int sg = ph - 8;
            #pragma unroll
            for (int j = 0; j < 2; ++j) {
                int kcol = (sg * 2 + j) * 16 + kh * 8;
                bf16x8 a0 = *(const bf16x8*)&h_lds[(mh * 64 +  0 + m31) * HPITCH + kcol];
                bf16x8 a1 = *(const bf16x8*)&h_lds[(mh * 64 + 32 + m31) * HPITCH + kcol];
                #pragma unroll
                for (int o = 0; o < 3; ++o) {
                    bf16x8 b = *(const bf16x8*)&stg[buf][((oj * 3 + o) * 2 + j) * 512 + lane * 8];
                    acc2[o * 2 + 0] = __builtin_amdgcn_mfma_f32_32x32x16_bf16(a0, b, acc2[o * 2 + 0], 0, 0, 0);
                    acc2[o * 2 + 1] = __builtin_amdgcn_mfma_f32_32x32x16_bf16(a1, b, acc2[o * 2 + 1], 0, 0, 0);
                }
            }
        }

        // barrier-2: all waves done consuming stage s (and h-writes landed, via lgkm
        // drain) before anyone's stage-(s+2) issue of the NEXT iteration can overwrite.
        asm volatile("s_waitcnt lgkmcnt(0)" ::: "memory");
        __builtin_amdgcn_sched_barrier(0);
        __builtin_amdgcn_s_barrier();
        __builtin_amdgcn_sched_barrier(0);
    }

    // ---- epilogue: plain bf16 stores to private partial slice (64B lines, L2-buffered)
    unsigned short* ypb = yp4 + ((size_t)(hs * NEXP + e) * CAP_TOK) * OUTD;
    #pragma unroll
    for (int o = 0; o < 3; ++o) {
        int col = (oj * 3 + o) * 32 + m31;
        #pragma unroll
        for (int ss2 = 0; ss2 < 2; ++ss2)
            #pragma unroll
            for (int rr = 0; rr < 16; ++rr) {
                int row = mh * 64 + ss2 * 32 + (rr & 3) + 8 * (rr >> 2) + 4 * kh;
                int pos = tb * 128 + row;
                if (pos < cntE)
                    ypb[(size_t)pos * OUTD + col] = f2bf(acc2[o * 2 + ss2][rr]);
            }
    }
}

// ----------- reduce: out = sum_k g_k * (sum_hs yp4[hs][e_k][pos_k] + b2[e_k]); bf16 partials
__global__ void reduce_kernel(const unsigned short* __restrict__ yp4,
                              const int* __restrict__ tokmap, const float* __restrict__ gmap,
                              const float* __restrict__ b2, float* __restrict__ out) {
    int gid = blockIdx.x * 256 + threadIdx.x;      // N_TOK * 48 threads
    int t = gid / 48, q = gid - t * 48;            // q: 8-col group
    int4   tm = ((const int4*)tokmap)[t];
    float2 g  = ((const float2*)gmap)[t];
    const size_t hstep = (size_t)NEXP * CAP_TOK * OUTD;
    const unsigned short* p0 = yp4 + ((size_t)tm.x * CAP_TOK + tm.y) * OUTD + q * 8;
    const unsigned short* p1 = yp4 + ((size_t)tm.z * CAP_TOK + tm.w) * OUTD + q * 8;
    float y0[8] = {0,0,0,0,0,0,0,0};
    float y1[8] = {0,0,0,0,0,0,0,0};
    #pragma unroll
    for (int h = 0; h < 4; ++h) {
        u16x8 a = __builtin_nontemporal_load((const u16x8*)(p0 + h * hstep));
        u16x8 b = __builtin_nontemporal_load((const u16x8*)(p1 + h * hstep));
        #pragma unroll
        for (int j = 0; j < 8; ++j) { y0[j] += bf2f(a[j]); y1[j] += bf2f(b[j]); }
    }
    const float* c0 = &b2[tm.x * OUTD + q * 8];
    const float* c1 = &b2[tm.z * OUTD + q * 8];
    f32x4 r0, r1;
    #pragma unroll
    for (int j = 0; j < 4; ++j) {
        r0[j] = g.x * (y0[j] + c0[j]) + g.y * (y1[j] + c1[j]);
        r1[j] = g.x * (y0[4 + j] + c0[4 + j]) + g.y * (y1[4 + j] + c1[4 + j]);
    }
    float* op = &out[(size_t)t * OUTD + q * 8];
    __builtin_nontemporal_store(r0, (f32x4*)op);
    __builtin_nontemporal_store(r1, (f32x4*)(op + 4));
}

// ---------------------------------------------------------------- launch
extern "C" void kernel_launch(void* const* d_in, const int* in_sizes, int n_in,
                              void* d_out, int out_size, void* d_ws, size_t ws_size,
                              hipStream_t stream) {
    const float* x  = (const float*)d_in[0];
    const float* Wg = (const float*)d_in[1];
    const float* bg = (const float*)d_in[2];
    const float* W1 = (const float*)d_in[3];
    const float* b1 = (const float*)d_in[4];
    const float* W2 = (const float*)d_in[5];
    const float* b2 = (const float*)d_in[6];
    float* out = (float*)d_out;

    char* ws = (char*)d_ws;                                    // all offsets 1KB-aligned
    int*            cnt    = (int*)ws;                         // 32 B
    int*            btok   = (int*)(ws + 1024);                // 256 KB
    int*            tokmap = (int*)(ws + 263168);              // 128 KB
    float*          gmap   = (float*)(ws + 394240);            // 64 KB
    unsigned short* xg     = (unsigned short*)(ws + 459776);   // 13.5 MB
    unsigned short* w1s    = (unsigned short*)(ws + 14615552); // 9.44 MB
    unsigned short* w2s    = (unsigned short*)(ws + 24052736); // 9.44 MB
    unsigned short* yp4    = (unsigned short*)(ws + 33489920); // 56.6 MB -> end ~90 MB

    // W1: K=DIM, N=HID -> NT=48, KT=24 ; W2: K=HID, N=OUTD -> NT=12, KT=96
    hipLaunchKernelGGL(swizzle_kernel, dim3(NEXP * 48 * 24 * 64 / 256), dim3(256), 0, stream,
                       W1, w1s, DIM, HID, 48, 24, cnt);
    hipLaunchKernelGGL(swizzle_kernel, dim3(NEXP * 12 * 96 * 64 / 256), dim3(256), 0, stream,
                       W2, w2s, HID, OUTD, 12, 96, (int*)nullptr);
    hipLaunchKernelGGL(router_kernel, dim3(N_TOK / 256), dim3(256), 0, stream,
                       x, Wg, bg, cnt, btok, tokmap, gmap);
    hipLaunchKernelGGL(gather_kernel, dim3(CAP_MT, NEXP), dim3(256), 0, stream,
                       x, cnt, btok, xg);
    hipLaunchKernelGGL(expert_kernel, dim3(NEXP * 4 * CAP_TB), dim3(512), 0, stream,
                       xg, w1s, w2s, b1, cnt, yp4);
    hipLaunchKernelGGL(reduce_kernel, dim3(N_TOK * 48 / 256), dim3(256), 0, stream,
                       yp4, tokmap, gmap, b2, out);
}

// Round 5
// 211.890 us; speedup vs baseline: 2.0412x; 1.4669x over previous
//
#include <hip/hip_runtime.h>
#include <cmath>

#define N_TOK 8192
#define DIM   384
#define NEXP  8
#define HID   1536
#define OUTD  384
#define CAP_MT 72        // 32-row gather tiles per expert (2304 tokens, mean 2048 + 6 sigma)
#define CAP_TOK 2304
#define CAP_TB 18        // 128-row blocks per expert

typedef __attribute__((ext_vector_type(8)))  __bf16 bf16x8;
typedef __attribute__((ext_vector_type(16))) float  f32x16;
typedef __attribute__((ext_vector_type(4)))  float  f32x4;          // nontemporal builtins
typedef __attribute__((ext_vector_type(8)))  unsigned short u16x8;  // nontemporal bf16 loads

__device__ __forceinline__ unsigned short f2bf(float f) {
    unsigned u = __float_as_uint(f);
    u += 0x7FFF + ((u >> 16) & 1);          // round-to-nearest-even
    return (unsigned short)(u >> 16);
}

__device__ __forceinline__ float bf2f(unsigned short s) {
    return __uint_as_float(((unsigned)s) << 16);
}

__device__ __forceinline__ float gelu_exact(float x) {
    return 0.5f * x * (1.0f + erff(x * 0.70710678118654752f));
}

// async global->LDS, 16B per lane; LDS dest = wave-uniform tile base (HW adds lane*16)
__device__ __forceinline__ void cp16(const unsigned short* g, unsigned short* l) {
    __builtin_amdgcn_global_load_lds(
        (const __attribute__((address_space(1))) unsigned int*)g,
        (__attribute__((address_space(3))) unsigned int*)l, 16, 0, 0);
}

// ------------------------------------------------- W[e][K][N] fp32 -> B-fragment order bf16
// dst[((e*NT + nt)*KT + kt)*64 + l][j] = bf16(src[e][kt*16 + (l>>5)*8 + j][nt*32 + (l&31)])
// Also zeroes cnt from block 0 when cnt != nullptr (saves a launch).
__global__ void swizzle_kernel(const float* __restrict__ src, unsigned short* __restrict__ dst,
                               int K, int N, int NT, int KT, int* __restrict__ cnt) {
    if (cnt && blockIdx.x == 0 && threadIdx.x < NEXP) cnt[threadIdx.x] = 0;
    int gid = blockIdx.x * blockDim.x + threadIdx.x;
    int total = NEXP * NT * KT * 64;
    if (gid >= total) return;
    int l  = gid & 63;
    int kt = (gid >> 6) % KT;
    int nt = ((gid >> 6) / KT) % NT;
    int e  = gid / (64 * KT * NT);
    const float* s = src + ((size_t)e * K + kt * 16 + (l >> 5) * 8) * N + nt * 32 + (l & 31);
    unsigned short r[8];
    #pragma unroll
    for (int j = 0; j < 8; ++j) r[j] = f2bf(s[(size_t)j * N]);
    *(uint4*)(dst + (size_t)gid * 8) = *(uint4*)r;
}

// ---------------------------------------------------------------- router
__global__ void router_kernel(const float* __restrict__ x, const float* __restrict__ Wg,
                              const float* __restrict__ bg, int* __restrict__ cnt,
                              int* __restrict__ btok, int* __restrict__ tokmap,
                              float* __restrict__ gmap) {
    __shared__ float WgL[DIM * NEXP];
    __shared__ int lcnt[NEXP];
    __shared__ int lbase[NEXP];
    int tid = threadIdx.x;
    for (int i = tid; i < DIM * NEXP; i += 256) WgL[i] = Wg[i];
    if (tid < NEXP) lcnt[tid] = 0;
    __syncthreads();

    int t = blockIdx.x * 256 + tid;
    float lg[NEXP];
    #pragma unroll
    for (int e = 0; e < NEXP; ++e) lg[e] = bg[e];

    const float4* xr = (const float4*)(x + (size_t)t * DIM);
    for (int d4 = 0; d4 < DIM / 4; ++d4) {
        float4 v = xr[d4];
        const float* wrow = &WgL[d4 * 4 * NEXP];
        #pragma unroll
        for (int e = 0; e < NEXP; ++e)
            lg[e] += v.x * wrow[e] + v.y * wrow[NEXP + e]
                   + v.z * wrow[2 * NEXP + e] + v.w * wrow[3 * NEXP + e];
    }

    float v0 = -INFINITY, v1 = -INFINITY; int i0 = 0, i1 = 0;
    #pragma unroll
    for (int e = 0; e < NEXP; ++e) {
        float v = lg[e];
        if (v > v0)      { v1 = v0; i1 = i0; v0 = v; i0 = e; }
        else if (v > v1) { v1 = v;  i1 = e; }
    }
    float e1 = expf(v1 - v0);
    float g0 = 1.f / (1.f + e1);
    float g1 = e1  / (1.f + e1);

    int p0 = atomicAdd(&lcnt[i0], 1);
    int p1 = atomicAdd(&lcnt[i1], 1);
    __syncthreads();
    if (tid < NEXP) lbase[tid] = atomicAdd(&cnt[tid], lcnt[tid]);
    __syncthreads();
    int o0 = lbase[i0] + p0, o1 = lbase[i1] + p1;
    btok[i0 * N_TOK + o0] = t;
    btok[i1 * N_TOK + o1] = t;
    ((int4*)tokmap)[t] = make_int4(i0, o0, i1, o1);
    ((float2*)gmap)[t] = make_float2(g0, g1);
}

// ------------------------------------------ gather x rows into A-fragment order (bf16)
__global__ void gather_kernel(const float* __restrict__ x, const int* __restrict__ cnt,
                              const int* __restrict__ btok, unsigned short* __restrict__ xg) {
    int mt = blockIdx.x, e = blockIdx.y;
    int cntE = cnt[e];
    if (mt * 32 >= cntE) return;
    int tid = threadIdx.x;                 // 256
    int m = tid & 31, kt0 = tid >> 5;      // 32 x 8
    int pos = mt * 32 + m;
    int idx = (pos < cntE) ? pos : cntE - 1;   // clamp pad rows (masked later)
    int tok = btok[e * N_TOK + idx];
    const float* xr = x + (size_t)tok * DIM;
    #pragma unroll
    for (int kk = 0; kk < 3; ++kk) {
        int kt = kt0 + kk * 8;
        #pragma unroll
        for (int kh = 0; kh < 2; ++kh) {
            float4 v0 = *(const float4*)(xr + kt * 16 + kh * 8);
            float4 v1 = *(const float4*)(xr + kt * 16 + kh * 8 + 4);
            unsigned short rr[8];
            rr[0] = f2bf(v0.x); rr[1] = f2bf(v0.y); rr[2] = f2bf(v0.z); rr[3] = f2bf(v0.w);
            rr[4] = f2bf(v1.x); rr[5] = f2bf(v1.y); rr[6] = f2bf(v1.z); rr[7] = f2bf(v1.w);
            *(uint4*)(xg + (size_t)(((e * CAP_MT + mt) * 24 + kt) * 64 + kh * 32 + m) * 8) =
                *(uint4*)rr;
        }
    }
}

// ---------------------------------------------------------------- GEMM1: h = gelu(xg@W1+b1)
// Unfused m97-regime GEMM: 256 thr / 4 waves, wave-tile 64x64, acc 64 regs/lane ->
// ~3 blocks/CU co-resident; independent blocks overlap each other's staging drains
// (the mechanism the fused 1-block/CU megakernel could never have).
// Epilogue: bias + exact gelu, transpose C-layout -> A-fragment tiles through the
// stage LDS with XOR swizzle ((row&7)<<4), store h tiles for GEMM2.
__global__ __launch_bounds__(256, 3) void gemm1_kernel(
        const unsigned short* __restrict__ xg, const unsigned short* __restrict__ w1s,
        const float* __restrict__ b1, const int* __restrict__ cnt,
        unsigned short* __restrict__ h) {
    int L = blockIdx.x;                   // e in low 3 bits: XCD pin
    int e = L & 7;
    int r = L >> 3;
    int nb = r % 12;                      // 128-col slice of HID
    int tb = r / 12;                      // 128-token block
    int cntE = cnt[e];
    if (tb * 128 >= cntE) return;

    __shared__ unsigned short stg[32 * 512];   // 32 KB: A tiles [0..15], B tiles [16..31]

    int tid = threadIdx.x;
    int wave = tid >> 6, lane = tid & 63;
    int m31 = lane & 31, kh = lane >> 5;
    int wm = wave & 1, wn = wave >> 1;    // 64-row half, 64-col half

    f32x16 acc[2][2];
    #pragma unroll
    for (int i = 0; i < 2; ++i)
        #pragma unroll
        for (int j = 0; j < 2; ++j)
            acc[i][j] = (f32x16){0.f,0.f,0.f,0.f,0.f,0.f,0.f,0.f,0.f,0.f,0.f,0.f,0.f,0.f,0.f,0.f};

    const unsigned short* xa = xg  + ((size_t)(e * CAP_MT + tb * 4) * 24) * 512;
    const unsigned short* wb = w1s + ((size_t)(e * 48 + nb * 4) * 24) * 512;

    for (int ks = 0; ks < 6; ++ks) {            // K = 384 = 6 x BK64
        __syncthreads();                         // stg free
        #pragma unroll
        for (int q = 0; q < 8; ++q) {            // 32 tiles, 8 cp16/wave
            int tl = wave * 8 + q;
            const unsigned short* src = (tl < 16)
                ? xa + ((size_t)((tl >> 2) * 24 + ks * 4 + (tl & 3))) * 512
                : wb + ((size_t)(((tl - 16) >> 2) * 24 + ks * 4 + (tl & 3))) * 512;
            cp16(src + lane * 8, &stg[tl * 512]);
        }
        __syncthreads();                         // drain: tiles visible
        #pragma unroll
        for (int kt = 0; kt < 4; ++kt) {
            bf16x8 a0 = *(const bf16x8*)&stg[((wm * 2 + 0) * 4 + kt) * 512 + lane * 8];
            bf16x8 a1 = *(const bf16x8*)&stg[((wm * 2 + 1) * 4 + kt) * 512 + lane * 8];
            bf16x8 b0 = *(const bf16x8*)&stg[(16 + (wn * 2 + 0) * 4 + kt) * 512 + lane * 8];
            bf16x8 b1v = *(const bf16x8*)&stg[(16 + (wn * 2 + 1) * 4 + kt) * 512 + lane * 8];
            acc[0][0] = __builtin_amdgcn_mfma_f32_32x32x16_bf16(a0, b0,  acc[0][0], 0, 0, 0);
            acc[0][1] = __builtin_amdgcn_mfma_f32_32x32x16_bf16(a0, b1v, acc[0][1], 0, 0, 0);
            acc[1][0] = __builtin_amdgcn_mfma_f32_32x32x16_bf16(a1, b0,  acc[1][0], 0, 0, 0);
            acc[1][1] = __builtin_amdgcn_mfma_f32_32x32x16_bf16(a1, b1v, acc[1][1], 0, 0, 0);
        }
    }

    // ---- epilogue: bias + gelu -> wave-private 8 KB LDS region (XOR-swizzled) ----
    __syncthreads();                             // all waves done reading stg
    char* hw = (char*)&stg[wave * 4096];         // 64 rows x 128 B
    float bv0 = b1[e * HID + nb * 128 + wn * 64 + m31];
    float bv1 = b1[e * HID + nb * 128 + wn * 64 + 32 + m31];
    #pragma unroll
    for (int im = 0; im < 2; ++im)
        #pragma unroll
        for (int in = 0; in < 2; ++in) {
            float bv = in ? bv1 : bv0;
            #pragma unroll
            for (int rr = 0; rr < 16; ++rr) {
                int row = im * 32 + (rr & 3) + 8 * (rr >> 2) + 4 * kh;   // local token row
                int col = in * 32 + m31;                                  // local hid col
                unsigned boff = (unsigned)(row * 128 + col * 2) ^ ((row & 7) << 4);
                *(unsigned short*)(hw + boff) = f2bf(gelu_exact(acc[im][in][rr] + bv));
            }
        }
    // wave-private RAW: compiler inserts lgkmcnt. Read back as A-fragment tiles, store.
    #pragma unroll
    for (int mtl = 0; mtl < 2; ++mtl)
        #pragma unroll
        for (int ktl = 0; ktl < 4; ++ktl) {
            int rowl = mtl * 32 + m31;
            int coll = ktl * 16 + kh * 8;
            unsigned boff = (unsigned)(rowl * 128 + coll * 2) ^ ((rowl & 7) << 4);
            uint4 v = *(const uint4*)(hw + boff);
            int mt = tb * 4 + wm * 2 + mtl;           // token tile (32 rows)
            int kt = nb * 8 + wn * 4 + ktl;           // hid tile (16 k)
            *(uint4*)(h + ((size_t)((e * CAP_MT + mt) * 96 + kt)) * 512 + lane * 8) = v;
        }
}

// ---------------------------------------------------------------- GEMM2: yp = h @ W2
// Same skeleton, K = 1536 (24 steps, well amortized). Full-K f32 accumulation ->
// single bf16 rounding (better than the old 4-way bf16 partial sum). Epilogue
// transposes to row-major yp via the same XOR-swizzled LDS path.
__global__ __launch_bounds__(256, 3) void gemm2_kernel(
        const unsigned short* __restrict__ h, const unsigned short* __restrict__ w2s,
        const int* __restrict__ cnt, unsigned short* __restrict__ yp) {
    int L = blockIdx.x;
    int e = L & 7;
    int r = L >> 3;
    int nb = r % 3;                        // 128-col slice of OUTD
    int tb = r / 3;                        // 128-token block
    int cntE = cnt[e];
    if (tb * 128 >= cntE) return;

    __shared__ unsigned short stg[32 * 512];

    int tid = threadIdx.x;
    int wave = tid >> 6, lane = tid & 63;
    int m31 = lane & 31, kh = lane >> 5;
    int wm = wave & 1, wn = wave >> 1;

    f32x16 acc[2][2];
    #pragma unroll
    for (int i = 0; i < 2; ++i)
        #pragma unroll
        for (int j = 0; j < 2; ++j)
            acc[i][j] = (f32x16){0.f,0.f,0.f,0.f,0.f,0.f,0.f,0.f,0.f,0.f,0.f,0.f,0.f,0.f,0.f,0.f};

    const unsigned short* xa = h   + ((size_t)(e * CAP_MT + tb * 4) * 96) * 512;
    const unsigned short* wb = w2s + ((size_t)(e * 12 + nb * 4) * 96) * 512;

    for (int ks = 0; ks < 24; ++ks) {           // K = 1536 = 24 x BK64
        __syncthreads();
        #pragma unroll
        for (int q = 0; q < 8; ++q) {
            int tl = wave * 8 + q;
            const unsigned short* src = (tl < 16)
                ? xa + ((size_t)((tl >> 2) * 96 + ks * 4 + (tl & 3))) * 512
                : wb + ((size_t)(((tl - 16) >> 2) * 96 + ks * 4 + (tl & 3))) * 512;
            cp16(src + lane * 8, &stg[tl * 512]);
        }
        __syncthreads();
        #pragma unroll
        for (int kt = 0; kt < 4; ++kt) {
            bf16x8 a0 = *(const bf16x8*)&stg[((wm * 2 + 0) * 4 + kt) * 512 + lane * 8];
            bf16x8 a1 = *(const bf16x8*)&stg[((wm * 2 + 1) * 4 + kt) * 512 + lane * 8];
            bf16x8 b0 = *(const bf16x8*)&stg[(16 + (wn * 2 + 0) * 4 + kt) * 512 + lane * 8];
            bf16x8 b1v = *(const bf16x8*)&stg[(16 + (wn * 2 + 1) * 4 + kt) * 512 + lane * 8];
            acc[0][0] = __builtin_amdgcn_mfma_f32_32x32x16_bf16(a0, b0,  acc[0][0], 0, 0, 0);
            acc[0][1] = __builtin_amdgcn_mfma_f32_32x32x16_bf16(a0, b1v, acc[0][1], 0, 0, 0);
            acc[1][0] = __builtin_amdgcn_mfma_f32_32x32x16_bf16(a1, b0,  acc[1][0], 0, 0, 0);
            acc[1][1] = __builtin_amdgcn_mfma_f32_32x32x16_bf16(a1, b1v, acc[1][1], 0, 0, 0);
        }
    }

    // ---- epilogue: transpose to row-major yp rows via XOR-swizzled LDS ----
    __syncthreads();
    char* hw = (char*)&stg[wave * 4096];
    #pragma unroll
    for (int im = 0; im < 2; ++im)
        #pragma unroll
        for (int in = 0; in < 2; ++in)
            #pragma unroll
            for (int rr = 0; rr < 16; ++rr) {
                int row = im * 32 + (rr & 3) + 8 * (rr >> 2) + 4 * kh;
                int col = in * 32 + m31;
                unsigned boff = (unsigned)(row * 128 + col * 2) ^ ((row & 7) << 4);
                *(unsigned short*)(hw + boff) = f2bf(acc[im][in][rr]);
            }
    int rl8 = lane >> 3, cc = lane & 7;          // 8 rows x 8 col-chunks per pass
    #pragma unroll
    for (int it = 0; it < 8; ++it) {
        int rowl = it * 8 + rl8;
        unsigned boff = (unsigned)(rowl * 128 + cc * 16) ^ ((rowl & 7) << 4);
        uint4 v = *(const uint4*)(hw + boff);
        int pos = tb * 128 + wm * 64 + rowl;     // < CAP_TOK always: in-bounds
        *(uint4*)(yp + (size_t)(e * CAP_TOK + pos) * OUTD + nb * 128 + wn * 64 + cc * 8) = v;
    }
}

// ----------- reduce: out = sum_k g_k * (yp[e_k][pos_k] + b2[e_k]); single full-K partial
__global__ void reduce_kernel(const unsigned short* __restrict__ yp,
                              const int* __restrict__ tokmap, const float* __restrict__ gmap,
                              const float* __restrict__ b2, float* __restrict__ out) {
    int gid = blockIdx.x * 256 + threadIdx.x;      // N_TOK * 48 threads
    int t = gid / 48, q = gid - t * 48;            // q: 8-col group
    int4   tm = ((const int4*)tokmap)[t];
    float2 g  = ((const float2*)gmap)[t];
    const unsigned short* p0 = yp + ((size_t)(tm.x * CAP_TOK + tm.y)) * OUTD + q * 8;
    const unsigned short* p1 = yp + ((size_t)(tm.z * CAP_TOK + tm.w)) * OUTD + q * 8;
    u16x8 a = __builtin_nontemporal_load((const u16x8*)p0);
    u16x8 b = __builtin_nontemporal_load((const u16x8*)p1);
    const float* c0 = &b2[tm.x * OUTD + q * 8];
    const float* c1 = &b2[tm.z * OUTD + q * 8];
    f32x4 r0, r1;
    #pragma unroll
    for (int j = 0; j < 4; ++j) {
        r0[j] = g.x * (bf2f(a[j]) + c0[j]) + g.y * (bf2f(b[j]) + c1[j]);
        r1[j] = g.x * (bf2f(a[4 + j]) + c0[4 + j]) + g.y * (bf2f(b[4 + j]) + c1[4 + j]);
    }
    float* op = &out[(size_t)t * OUTD + q * 8];
    __builtin_nontemporal_store(r0, (f32x4*)op);
    __builtin_nontemporal_store(r1, (f32x4*)(op + 4));
}

// ---------------------------------------------------------------- launch
extern "C" void kernel_launch(void* const* d_in, const int* in_sizes, int n_in,
                              void* d_out, int out_size, void* d_ws, size_t ws_size,
                              hipStream_t stream) {
    const float* x  = (const float*)d_in[0];
    const float* Wg = (const float*)d_in[1];
    const float* bg = (const float*)d_in[2];
    const float* W1 = (const float*)d_in[3];
    const float* b1 = (const float*)d_in[4];
    const float* W2 = (const float*)d_in[5];
    const float* b2 = (const float*)d_in[6];
    float* out = (float*)d_out;

    char* ws = (char*)d_ws;                                    // all offsets 1KB-aligned
    int*            cnt    = (int*)ws;                         // 32 B
    int*            btok   = (int*)(ws + 1024);                // 256 KB
    int*            tokmap = (int*)(ws + 263168);              // 128 KB
    float*          gmap   = (float*)(ws + 394240);            // 64 KB
    unsigned short* xg     = (unsigned short*)(ws + 459776);   // 13.5 MB (tiles 8x72x24)
    unsigned short* w1s    = (unsigned short*)(ws + 14615552); // 9.44 MB
    unsigned short* w2s    = (unsigned short*)(ws + 24052736); // 9.44 MB
    unsigned short* h      = (unsigned short*)(ws + 33489920); // 56.6 MB (tiles 8x72x96)
    // yp (8 x 2304 x 384 bf16 = 13.5 MB) aliases the xg slot: gemm2 runs strictly after
    // gemm1's last read of xg (same stream), and next iteration's gather fully rewrites
    // the tiles gemm1 reads. Keeps workspace footprint identical to the fused version.
    unsigned short* yp     = xg;

    // W1: K=DIM, N=HID -> NT=48, KT=24 ; W2: K=HID, N=OUTD -> NT=12, KT=96
    hipLaunchKernelGGL(swizzle_kernel, dim3(NEXP * 48 * 24 * 64 / 256), dim3(256), 0, stream,
                       W1, w1s, DIM, HID, 48, 24, cnt);
    hipLaunchKernelGGL(swizzle_kernel, dim3(NEXP * 12 * 96 * 64 / 256), dim3(256), 0, stream,
                       W2, w2s, HID, OUTD, 12, 96, (int*)nullptr);
    hipLaunchKernelGGL(router_kernel, dim3(N_TOK / 256), dim3(256), 0, stream,
                       x, Wg, bg, cnt, btok, tokmap, gmap);
    hipLaunchKernelGGL(gather_kernel, dim3(CAP_MT, NEXP), dim3(256), 0, stream,
                       x, cnt, btok, xg);
    hipLaunchKernelGGL(gemm1_kernel, dim3(NEXP * 12 * CAP_TB), dim3(256), 0, stream,
                       xg, w1s, b1, cnt, h);
    hipLaunchKernelGGL(gemm2_kernel, dim3(NEXP * 3 * CAP_TB), dim3(256), 0, stream,
                       h, w2s, cnt, yp);
    hipLaunchKernelGGL(reduce_kernel, dim3(N_TOK * 48 / 256), dim3(256), 0, stream,
                       yp, tokmap, gmap, b2, out);
}

// Round 7
// 197.971 us; speedup vs baseline: 2.1847x; 1.0703x over previous
//
#include <hip/hip_runtime.h>
#include <cmath>

#define N_TOK 8192
#define DIM   384
#define NEXP  8
#define HID   1536
#define OUTD  384
#define CAP_MT 72        // 32-row gather tiles per expert (2304 tokens, mean 2048 + 6 sigma)
#define CAP_TOK 2304
#define CAP_TB 18        // 128-row blocks per expert

typedef __attribute__((ext_vector_type(8)))  __bf16 bf16x8;
typedef __attribute__((ext_vector_type(16))) float  f32x16;
typedef __attribute__((ext_vector_type(4)))  float  f32x4;          // nontemporal builtins
typedef __attribute__((ext_vector_type(8)))  unsigned short u16x8;  // nontemporal bf16 loads

__device__ __forceinline__ unsigned short f2bf(float f) {
    unsigned u = __float_as_uint(f);
    u += 0x7FFF + ((u >> 16) & 1);          // round-to-nearest-even
    return (unsigned short)(u >> 16);
}

__device__ __forceinline__ float bf2f(unsigned short s) {
    return __uint_as_float(((unsigned)s) << 16);
}

// exact-to-bf16 gelu: Abramowitz-Stegun 7.1.26 erf (max abs err 1.5e-7, far below the
// bf16 quantum of h). ~12 VALU ops vs ~25-30 for libm erff -> cuts the epilogue tail.
__device__ __forceinline__ float gelu_fast(float x) {
    float a  = 0.70710678118654752f * x;
    float ax = fabsf(a);
    float t  = 1.0f / (1.0f + 0.3275911f * ax);
    float y  = t * (0.254829592f + t * (-0.284496736f + t * (1.421413741f
             + t * (-1.453152027f + t * 1.061405429f))));
    float er = 1.0f - y * __expf(-ax * ax);
    er = copysignf(er, a);
    return 0.5f * x * (1.0f + er);
}

// async global->LDS, 16B per lane; LDS dest = wave-uniform tile base (HW adds lane*16)
__device__ __forceinline__ void cp16(const unsigned short* g, unsigned short* l) {
    __builtin_amdgcn_global_load_lds(
        (const __attribute__((address_space(1))) unsigned int*)g,
        (__attribute__((address_space(3))) unsigned int*)l, 16, 0, 0);
}

// ------------------------- merged W1+W2 swizzle: fp32 [e][K][N] -> B-fragment bf16 tiles
// dst[((e*NT + nt)*KT + kt)*64 + l][j] = bf16(src[e][kt*16 + (l>>5)*8 + j][nt*32 + (l&31)])
// T1 = NEXP*48*24*64 = 589824 (W1), T2 = NEXP*12*96*64 = 589824 (W2) -> grid 4608x256
// exactly. (R6 bug: grid 4032 left the last quarter of w2s unwritten -> absmax 0.55.)
// Block 0 zeroes cnt.
__global__ void swizzle_kernel(const float* __restrict__ W1, const float* __restrict__ W2,
                               unsigned short* __restrict__ w1s, unsigned short* __restrict__ w2s,
                               int* __restrict__ cnt) {
    if (blockIdx.x == 0 && threadIdx.x < NEXP) cnt[threadIdx.x] = 0;
    int gid = blockIdx.x * blockDim.x + threadIdx.x;
    const int T1 = NEXP * 48 * 24 * 64;        // 589824 threads for W1
    const int T2 = NEXP * 12 * 96 * 64;        // 589824 threads for W2
    const float* src; unsigned short* dst; int K, N, NT, KT, g;
    if (gid < T1)           { src = W1; dst = w1s; K = DIM; N = HID;  NT = 48; KT = 24; g = gid; }
    else if (gid < T1 + T2) { src = W2; dst = w2s; K = HID; N = OUTD; NT = 12; KT = 96; g = gid - T1; }
    else return;
    int l  = g & 63;
    int kt = (g >> 6) % KT;
    int nt = ((g >> 6) / KT) % NT;
    int e  = g / (64 * KT * NT);
    const float* s = src + ((size_t)e * K + kt * 16 + (l >> 5) * 8) * N + nt * 32 + (l & 31);
    unsigned short r[8];
    #pragma unroll
    for (int j = 0; j < 8; ++j) r[j] = f2bf(s[(size_t)j * N]);
    *(uint4*)(dst + (size_t)g * 8) = *(uint4*)r;
}

// ---------------------------------------------------------------- router
// 256 blocks x 256 thr (8x the old 32-block launch): 32 tokens/block, 8 threads/token.
// Per-instruction the 8 segs of 8 tokens read 8 contiguous 128B chunks (fully
// coalesced vs the old 16B-per-1536B-stride pattern). Wg staged TRANSPOSED [e][ch] in
// LDS so the per-e float4 reads are bank-spread. Butterfly __shfl_xor over the 3 seg
// bits reduces partial logits; top-2/gates/atomics unchanged, on seg==0 lanes.
__global__ void router_kernel(const float* __restrict__ x, const float* __restrict__ Wg,
                              const float* __restrict__ bg, int* __restrict__ cnt,
                              int* __restrict__ btok, int* __restrict__ tokmap,
                              float* __restrict__ gmap) {
    __shared__ float WgL[NEXP * DIM];          // transposed: WgL[e*DIM + ch]
    __shared__ int lcnt[NEXP];
    __shared__ int lbase[NEXP];
    int tid = threadIdx.x;
    for (int i = tid; i < DIM * NEXP; i += 256) {
        int ch = i >> 3, e = i & 7;            // Wg row-major read = coalesced
        WgL[e * DIM + ch] = Wg[i];
    }
    if (tid < NEXP) lcnt[tid] = 0;
    __syncthreads();

    int tl  = tid >> 3;                        // token-in-block 0..31
    int seg = tid & 7;                         // channel segment 0..7 (lane bits 2:0)
    int t   = blockIdx.x * 32 + tl;

    float lg[NEXP] = {0.f, 0.f, 0.f, 0.f, 0.f, 0.f, 0.f, 0.f};
    const float* xr = x + (size_t)t * DIM;
    #pragma unroll
    for (int d4 = 0; d4 < 12; ++d4) {
        float4 v = *(const float4*)(xr + d4 * 32 + seg * 4);
        #pragma unroll
        for (int e = 0; e < NEXP; ++e) {
            float4 w = *(const float4*)&WgL[e * DIM + d4 * 32 + seg * 4];
            lg[e] += v.x * w.x + v.y * w.y + v.z * w.z + v.w * w.w;
        }
    }
    // reduce the 8 segments (lane bits 0..2) per token
    #pragma unroll
    for (int off = 1; off < 8; off <<= 1)
        #pragma unroll
        for (int e = 0; e < NEXP; ++e)
            lg[e] += __shfl_xor(lg[e], off);

    int p0 = 0, p1 = 0, i0 = 0, i1 = 0;
    float g0 = 0.f, g1 = 0.f;
    if (seg == 0) {
        float v0 = -INFINITY, v1 = -INFINITY;
        #pragma unroll
        for (int e = 0; e < NEXP; ++e) {
            float v = lg[e] + bg[e];
            if (v > v0)      { v1 = v0; i1 = i0; v0 = v; i0 = e; }
            else if (v > v1) { v1 = v;  i1 = e; }
        }
        float e1 = expf(v1 - v0);
        g0 = 1.f / (1.f + e1);
        g1 = e1  / (1.f + e1);
        p0 = atomicAdd(&lcnt[i0], 1);
        p1 = atomicAdd(&lcnt[i1], 1);
    }
    __syncthreads();
    if (tid < NEXP) lbase[tid] = atomicAdd(&cnt[tid], lcnt[tid]);
    __syncthreads();
    if (seg == 0) {
        int o0 = lbase[i0] + p0, o1 = lbase[i1] + p1;
        btok[i0 * N_TOK + o0] = t;
        btok[i1 * N_TOK + o1] = t;
        ((int4*)tokmap)[t] = make_int4(i0, o0, i1, o1);
        ((float2*)gmap)[t] = make_float2(g0, g1);
    }
}

// ------------------------------------------ gather x rows into A-fragment order (bf16)
__global__ void gather_kernel(const float* __restrict__ x, const int* __restrict__ cnt,
                              const int* __restrict__ btok, unsigned short* __restrict__ xg) {
    int mt = blockIdx.x, e = blockIdx.y;
    int cntE = cnt[e];
    if (mt * 32 >= cntE) return;
    int tid = threadIdx.x;                 // 256
    int m = tid & 31, kt0 = tid >> 5;      // 32 x 8
    int pos = mt * 32 + m;
    int idx = (pos < cntE) ? pos : cntE - 1;   // clamp pad rows (masked later)
    int tok = btok[e * N_TOK + idx];
    const float* xr = x + (size_t)tok * DIM;
    #pragma unroll
    for (int kk = 0; kk < 3; ++kk) {
        int kt = kt0 + kk * 8;
        #pragma unroll
        for (int kh = 0; kh < 2; ++kh) {
            float4 v0 = *(const float4*)(xr + kt * 16 + kh * 8);
            float4 v1 = *(const float4*)(xr + kt * 16 + kh * 8 + 4);
            unsigned short rr[8];
            rr[0] = f2bf(v0.x); rr[1] = f2bf(v0.y); rr[2] = f2bf(v0.z); rr[3] = f2bf(v0.w);
            rr[4] = f2bf(v1.x); rr[5] = f2bf(v1.y); rr[6] = f2bf(v1.z); rr[7] = f2bf(v1.w);
            *(uint4*)(xg + (size_t)(((e * CAP_MT + mt) * 24 + kt) * 64 + kh * 32 + m) * 8) =
                *(uint4*)rr;
        }
    }
}

// ---------------------------------------------------------------- GEMM1: h = gelu(xg@W1+b1)
// Unfused m97-regime GEMM: 256 thr / 4 waves, wave-tile 64x64, acc 64 regs/lane ->
// multi-block/CU; independent blocks overlap each other's staging drains (R5: verified,
// 120 -> 46 us vs the fused megakernel). Epilogue: bias + gelu_fast, transpose
// C-layout -> A-fragment tiles through stage LDS with XOR swizzle ((row&7)<<4).
__global__ __launch_bounds__(256, 3) void gemm1_kernel(
        const unsigned short* __restrict__ xg, const unsigned short* __restrict__ w1s,
        const float* __restrict__ b1, const int* __restrict__ cnt,
        unsigned short* __restrict__ h) {
    int L = blockIdx.x;                   // e in low 3 bits: XCD pin
    int e = L & 7;
    int r = L >> 3;
    int nb = r % 12;                      // 128-col slice of HID
    int tb = r / 12;                      // 128-token block
    int cntE = cnt[e];
    if (tb * 128 >= cntE) return;

    __shared__ unsigned short stg[32 * 512];   // 32 KB: A tiles [0..15], B tiles [16..31]

    int tid = threadIdx.x;
    int wave = tid >> 6, lane = tid & 63;
    int m31 = lane & 31, kh = lane >> 5;
    int wm = wave & 1, wn = wave >> 1;    // 64-row half, 64-col half

    f32x16 acc[2][2];
    #pragma unroll
    for (int i = 0; i < 2; ++i)
        #pragma unroll
        for (int j = 0; j < 2; ++j)
            acc[i][j] = (f32x16){0.f,0.f,0.f,0.f,0.f,0.f,0.f,0.f,0.f,0.f,0.f,0.f,0.f,0.f,0.f,0.f};

    const unsigned short* xa = xg  + ((size_t)(e * CAP_MT + tb * 4) * 24) * 512;
    const unsigned short* wb = w1s + ((size_t)(e * 48 + nb * 4) * 24) * 512;

    for (int ks = 0; ks < 6; ++ks) {            // K = 384 = 6 x BK64
        __syncthreads();                         // stg free
        #pragma unroll
        for (int q = 0; q < 8; ++q) {            // 32 tiles, 8 cp16/wave
            int tl = wave * 8 + q;
            const unsigned short* src = (tl < 16)
                ? xa + ((size_t)((tl >> 2) * 24 + ks * 4 + (tl & 3))) * 512
                : wb + ((size_t)(((tl - 16) >> 2) * 24 + ks * 4 + (tl & 3))) * 512;
            cp16(src + lane * 8, &stg[tl * 512]);
        }
        __syncthreads();                         // drain: tiles visible
        #pragma unroll
        for (int kt = 0; kt < 4; ++kt) {
            bf16x8 a0 = *(const bf16x8*)&stg[((wm * 2 + 0) * 4 + kt) * 512 + lane * 8];
            bf16x8 a1 = *(const bf16x8*)&stg[((wm * 2 + 1) * 4 + kt) * 512 + lane * 8];
            bf16x8 b0 = *(const bf16x8*)&stg[(16 + (wn * 2 + 0) * 4 + kt) * 512 + lane * 8];
            bf16x8 b1v = *(const bf16x8*)&stg[(16 + (wn * 2 + 1) * 4 + kt) * 512 + lane * 8];
            acc[0][0] = __builtin_amdgcn_mfma_f32_32x32x16_bf16(a0, b0,  acc[0][0], 0, 0, 0);
            acc[0][1] = __builtin_amdgcn_mfma_f32_32x32x16_bf16(a0, b1v, acc[0][1], 0, 0, 0);
            acc[1][0] = __builtin_amdgcn_mfma_f32_32x32x16_bf16(a1, b0,  acc[1][0], 0, 0, 0);
            acc[1][1] = __builtin_amdgcn_mfma_f32_32x32x16_bf16(a1, b1v, acc[1][1], 0, 0, 0);
        }
    }

    // ---- epilogue: bias + gelu -> wave-private 8 KB LDS region (XOR-swizzled) ----
    __syncthreads();                             // all waves done reading stg
    char* hw = (char*)&stg[wave * 4096];         // 64 rows x 128 B
    float bv0 = b1[e * HID + nb * 128 + wn * 64 + m31];
    float bv1 = b1[e * HID + nb * 128 + wn * 64 + 32 + m31];
    #pragma unroll
    for (int im = 0; im < 2; ++im)
        #pragma unroll
        for (int in = 0; in < 2; ++in) {
            float bv = in ? bv1 : bv0;
            #pragma unroll
            for (int rr = 0; rr < 16; ++rr) {
                int row = im * 32 + (rr & 3) + 8 * (rr >> 2) + 4 * kh;   // local token row
                int col = in * 32 + m31;                                  // local hid col
                unsigned boff = (unsigned)(row * 128 + col * 2) ^ ((row & 7) << 4);
                *(unsigned short*)(hw + boff) = f2bf(gelu_fast(acc[im][in][rr] + bv));
            }
        }
    // wave-private RAW: compiler inserts lgkmcnt. Read back as A-fragment tiles, store.
    #pragma unroll
    for (int mtl = 0; mtl < 2; ++mtl)
        #pragma unroll
        for (int ktl = 0; ktl < 4; ++ktl) {
            int rowl = mtl * 32 + m31;
            int coll = ktl * 16 + kh * 8;
            unsigned boff = (unsigned)(rowl * 128 + coll * 2) ^ ((rowl & 7) << 4);
            uint4 v = *(const uint4*)(hw + boff);
            int mt = tb * 4 + wm * 2 + mtl;           // token tile (32 rows)
            int kt = nb * 8 + wn * 4 + ktl;           // hid tile (16 k)
            *(uint4*)(h + ((size_t)((e * CAP_MT + mt) * 96 + kt)) * 512 + lane * 8) = v;
        }
}

// ---------------------------------------------------------------- GEMM2: yp = h @ W2
// Same skeleton, K = 1536 (24 steps, well amortized). Full-K f32 accumulation ->
// single bf16 rounding. Epilogue transposes to row-major yp via XOR-swizzled LDS.
__global__ __launch_bounds__(256, 3) void gemm2_kernel(
        const unsigned short* __restrict__ h, const unsigned short* __restrict__ w2s,
        const int* __restrict__ cnt, unsigned short* __restrict__ yp) {
    int L = blockIdx.x;
    int e = L & 7;
    int r = L >> 3;
    int nb = r % 3;                        // 128-col slice of OUTD
    int tb = r / 3;                        // 128-token block
    int cntE = cnt[e];
    if (tb * 128 >= cntE) return;

    __shared__ unsigned short stg[32 * 512];

    int tid = threadIdx.x;
    int wave = tid >> 6, lane = tid & 63;
    int m31 = lane & 31, kh = lane >> 5;
    int wm = wave & 1, wn = wave >> 1;

    f32x16 acc[2][2];
    #pragma unroll
    for (int i = 0; i < 2; ++i)
        #pragma unroll
        for (int j = 0; j < 2; ++j)
            acc[i][j] = (f32x16){0.f,0.f,0.f,0.f,0.f,0.f,0.f,0.f,0.f,0.f,0.f,0.f,0.f,0.f,0.f,0.f};

    const unsigned short* xa = h   + ((size_t)(e * CAP_MT + tb * 4) * 96) * 512;
    const unsigned short* wb = w2s + ((size_t)(e * 12 + nb * 4) * 96) * 512;

    for (int ks = 0; ks < 24; ++ks) {           // K = 1536 = 24 x BK64
        __syncthreads();
        #pragma unroll
        for (int q = 0; q < 8; ++q) {
            int tl = wave * 8 + q;
            const unsigned short* src = (tl < 16)
                ? xa + ((size_t)((tl >> 2) * 96 + ks * 4 + (tl & 3))) * 512
                : wb + ((size_t)(((tl - 16) >> 2) * 96 + ks * 4 + (tl & 3))) * 512;
            cp16(src + lane * 8, &stg[tl * 512]);
        }
        __syncthreads();
        #pragma unroll
        for (int kt = 0; kt < 4; ++kt) {
            bf16x8 a0 = *(const bf16x8*)&stg[((wm * 2 + 0) * 4 + kt) * 512 + lane * 8];
            bf16x8 a1 = *(const bf16x8*)&stg[((wm * 2 + 1) * 4 + kt) * 512 + lane * 8];
            bf16x8 b0 = *(const bf16x8*)&stg[(16 + (wn * 2 + 0) * 4 + kt) * 512 + lane * 8];
            bf16x8 b1v = *(const bf16x8*)&stg[(16 + (wn * 2 + 1) * 4 + kt) * 512 + lane * 8];
            acc[0][0] = __builtin_amdgcn_mfma_f32_32x32x16_bf16(a0, b0,  acc[0][0], 0, 0, 0);
            acc[0][1] = __builtin_amdgcn_mfma_f32_32x32x16_bf16(a0, b1v, acc[0][1], 0, 0, 0);
            acc[1][0] = __builtin_amdgcn_mfma_f32_32x32x16_bf16(a1, b0,  acc[1][0], 0, 0, 0);
            acc[1][1] = __builtin_amdgcn_mfma_f32_32x32x16_bf16(a1, b1v, acc[1][1], 0, 0, 0);
        }
    }

    // ---- epilogue: transpose to row-major yp rows via XOR-swizzled LDS ----
    __syncthreads();
    char* hw = (char*)&stg[wave * 4096];
    #pragma unroll
    for (int im = 0; im < 2; ++im)
        #pragma unroll
        for (int in = 0; in < 2; ++in)
            #pragma unroll
            for (int rr = 0; rr < 16; ++rr) {
                int row = im * 32 + (rr & 3) + 8 * (rr >> 2) + 4 * kh;
                int col = in * 32 + m31;
                unsigned boff = (unsigned)(row * 128 + col * 2) ^ ((row & 7) << 4);
                *(unsigned short*)(hw + boff) = f2bf(acc[im][in][rr]);
            }
    int rl8 = lane >> 3, cc = lane & 7;          // 8 rows x 8 col-chunks per pass
    #pragma unroll
    for (int it = 0; it < 8; ++it) {
        int rowl = it * 8 + rl8;
        unsigned boff = (unsigned)(rowl * 128 + cc * 16) ^ ((rowl & 7) << 4);
        uint4 v = *(const uint4*)(hw + boff);
        int pos = tb * 128 + wm * 64 + rowl;     // < CAP_TOK always: in-bounds
        *(uint4*)(yp + (size_t)(e * CAP_TOK + pos) * OUTD + nb * 128 + wn * 64 + cc * 8) = v;
    }
}

// ----------- reduce: out = sum_k g_k * (yp[e_k][pos_k] + b2[e_k]); single full-K partial
__global__ void reduce_kernel(const unsigned short* __restrict__ yp,
                              const int* __restrict__ tokmap, const float* __restrict__ gmap,
                              const float* __restrict__ b2, float* __restrict__ out) {
    int gid = blockIdx.x * 256 + threadIdx.x;      // N_TOK * 48 threads
    int t = gid / 48, q = gid - t * 48;            // q: 8-col group
    int4   tm = ((const int4*)tokmap)[t];
    float2 g  = ((const float2*)gmap)[t];
    const unsigned short* p0 = yp + ((size_t)(tm.x * CAP_TOK + tm.y)) * OUTD + q * 8;
    const unsigned short* p1 = yp + ((size_t)(tm.z * CAP_TOK + tm.w)) * OUTD + q * 8;
    u16x8 a = __builtin_nontemporal_load((const u16x8*)p0);
    u16x8 b = __builtin_nontemporal_load((const u16x8*)p1);
    const float* c0 = &b2[tm.x * OUTD + q * 8];
    const float* c1 = &b2[tm.z * OUTD + q * 8];
    f32x4 r0, r1;
    #pragma unroll
    for (int j = 0; j < 4; ++j) {
        r0[j] = g.x * (bf2f(a[j]) + c0[j]) + g.y * (bf2f(b[j]) + c1[j]);
        r1[j] = g.x * (bf2f(a[4 + j]) + c0[4 + j]) + g.y * (bf2f(b[4 + j]) + c1[4 + j]);
    }
    float* op = &out[(size_t)t * OUTD + q * 8];
    __builtin_nontemporal_store(r0, (f32x4*)op);
    __builtin_nontemporal_store(r1, (f32x4*)(op + 4));
}

// ---------------------------------------------------------------- launch
extern "C" void kernel_launch(void* const* d_in, const int* in_sizes, int n_in,
                              void* d_out, int out_size, void* d_ws, size_t ws_size,
                              hipStream_t stream) {
    const float* x  = (const float*)d_in[0];
    const float* Wg = (const float*)d_in[1];
    const float* bg = (const float*)d_in[2];
    const float* W1 = (const float*)d_in[3];
    const float* b1 = (const float*)d_in[4];
    const float* W2 = (const float*)d_in[5];
    const float* b2 = (const float*)d_in[6];
    float* out = (float*)d_out;

    char* ws = (char*)d_ws;                                    // all offsets 1KB-aligned
    int*            cnt    = (int*)ws;                         // 32 B
    int*            btok   = (int*)(ws + 1024);                // 256 KB
    int*            tokmap = (int*)(ws + 263168);              // 128 KB
    float*          gmap   = (float*)(ws + 394240);            // 64 KB
    unsigned short* xg     = (unsigned short*)(ws + 459776);   // 13.5 MB (tiles 8x72x24)
    unsigned short* w1s    = (unsigned short*)(ws + 14615552); // 9.44 MB
    unsigned short* w2s    = (unsigned short*)(ws + 24052736); // 9.44 MB
    unsigned short* h      = (unsigned short*)(ws + 33489920); // 56.6 MB (tiles 8x72x96)
    // yp (8 x 2304 x 384 bf16 = 13.5 MB) aliases the xg slot: gemm2 runs strictly after
    // gemm1's last read of xg (same stream), and next iteration's gather fully rewrites
    // the tiles gemm1 reads. Keeps workspace footprint identical.
    unsigned short* yp     = xg;

    // merged W1+W2 swizzle: (589824 + 589824) / 256 = 4608 blocks exactly
    hipLaunchKernelGGL(swizzle_kernel, dim3(4608), dim3(256), 0, stream,
                       W1, W2, w1s, w2s, cnt);
    hipLaunchKernelGGL(router_kernel, dim3(N_TOK / 32), dim3(256), 0, stream,
                       x, Wg, bg, cnt, btok, tokmap, gmap);
    hipLaunchKernelGGL(gather_kernel, dim3(CAP_MT, NEXP), dim3(256), 0, stream,
                       x, cnt, btok, xg);
    hipLaunchKernelGGL(gemm1_kernel, dim3(NEXP * 12 * CAP_TB), dim3(256), 0, stream,
                       xg, w1s, b1, cnt, h);
    hipLaunchKernelGGL(gemm2_kernel, dim3(NEXP * 3 * CAP_TB), dim3(256), 0, stream,
                       h, w2s, cnt, yp);
    hipLaunchKernelGGL(reduce_kernel, dim3(N_TOK * 48 / 256), dim3(256), 0, stream,
                       yp, tokmap, gmap, b2, out);
}

// Round 8
// 182.283 us; speedup vs baseline: 2.3727x; 1.0861x over previous
//
#include <hip/hip_runtime.h>
#include <cmath>

#define N_TOK 8192
#define DIM   384
#define NEXP  8
#define HID   1536
#define OUTD  384
#define CAP_MT 72        // 32-row gather tiles per expert (2304 tokens, mean 2048 + 6 sigma)
#define CAP_TOK 2304
#define CAP_TB 18        // 128-row blocks per expert

typedef __attribute__((ext_vector_type(8)))  __bf16 bf16x8;
typedef __attribute__((ext_vector_type(16))) float  f32x16;
typedef __attribute__((ext_vector_type(4)))  float  f32x4;          // nontemporal builtins
typedef __attribute__((ext_vector_type(8)))  unsigned short u16x8;  // nontemporal bf16 loads

__device__ __forceinline__ unsigned short f2bf(float f) {
    unsigned u = __float_as_uint(f);
    u += 0x7FFF + ((u >> 16) & 1);          // round-to-nearest-even
    return (unsigned short)(u >> 16);
}

__device__ __forceinline__ float bf2f(unsigned short s) {
    return __uint_as_float(((unsigned)s) << 16);
}

// R7 lesson: A&S-polynomial gelu with a (non-fast-math) IEEE divide + __expf is SLOWER
// than libm erff (VALUBusy 43->56%, gemm1 46->51 us). Reverted to the measured-fast form.
__device__ __forceinline__ float gelu_exact(float x) {
    return 0.5f * x * (1.0f + erff(x * 0.70710678118654752f));
}

// async global->LDS, 16B per lane; LDS dest = wave-uniform tile base (HW adds lane*16)
__device__ __forceinline__ void cp16(const unsigned short* g, unsigned short* l) {
    __builtin_amdgcn_global_load_lds(
        (const __attribute__((address_space(1))) unsigned int*)g,
        (__attribute__((address_space(3))) unsigned int*)l, 16, 0, 0);
}

// ------------------------- merged W1+W2 swizzle: fp32 [e][K][N] -> B-fragment bf16 tiles
// dst[((e*NT + nt)*KT + kt)*64 + l][j] = bf16(src[e][kt*16 + (l>>5)*8 + j][nt*32 + (l&31)])
// T1 = T2 = 589824 threads -> grid 4608x256 exactly. Block 0 zeroes cnt.
__global__ void swizzle_kernel(const float* __restrict__ W1, const float* __restrict__ W2,
                               unsigned short* __restrict__ w1s, unsigned short* __restrict__ w2s,
                               int* __restrict__ cnt) {
    if (blockIdx.x == 0 && threadIdx.x < NEXP) cnt[threadIdx.x] = 0;
    int gid = blockIdx.x * blockDim.x + threadIdx.x;
    const int T1 = NEXP * 48 * 24 * 64;        // 589824 threads for W1
    const int T2 = NEXP * 12 * 96 * 64;        // 589824 threads for W2
    const float* src; unsigned short* dst; int K, N, NT, KT, g;
    if (gid < T1)           { src = W1; dst = w1s; K = DIM; N = HID;  NT = 48; KT = 24; g = gid; }
    else if (gid < T1 + T2) { src = W2; dst = w2s; K = HID; N = OUTD; NT = 12; KT = 96; g = gid - T1; }
    else return;
    int l  = g & 63;
    int kt = (g >> 6) % KT;
    int nt = ((g >> 6) / KT) % NT;
    int e  = g / (64 * KT * NT);
    const float* s = src + ((size_t)e * K + kt * 16 + (l >> 5) * 8) * N + nt * 32 + (l & 31);
    unsigned short r[8];
    #pragma unroll
    for (int j = 0; j < 8; ++j) r[j] = f2bf(s[(size_t)j * N]);
    *(uint4*)(dst + (size_t)g * 8) = *(uint4*)r;
}

// ---------------------------------------------------------------- router
// 256 blocks x 256 thr: 32 tokens/block, 8 threads/token, coalesced 128B chunks;
// Wg staged transposed; __shfl_xor butterfly over seg bits. (R7: verified win.)
__global__ void router_kernel(const float* __restrict__ x, const float* __restrict__ Wg,
                              const float* __restrict__ bg, int* __restrict__ cnt,
                              int* __restrict__ btok, int* __restrict__ tokmap,
                              float* __restrict__ gmap) {
    __shared__ float WgL[NEXP * DIM];          // transposed: WgL[e*DIM + ch]
    __shared__ int lcnt[NEXP];
    __shared__ int lbase[NEXP];
    int tid = threadIdx.x;
    for (int i = tid; i < DIM * NEXP; i += 256) {
        int ch = i >> 3, e = i & 7;            // Wg row-major read = coalesced
        WgL[e * DIM + ch] = Wg[i];
    }
    if (tid < NEXP) lcnt[tid] = 0;
    __syncthreads();

    int tl  = tid >> 3;                        // token-in-block 0..31
    int seg = tid & 7;                         // channel segment 0..7 (lane bits 2:0)
    int t   = blockIdx.x * 32 + tl;

    float lg[NEXP] = {0.f, 0.f, 0.f, 0.f, 0.f, 0.f, 0.f, 0.f};
    const float* xr = x + (size_t)t * DIM;
    #pragma unroll
    for (int d4 = 0; d4 < 12; ++d4) {
        float4 v = *(const float4*)(xr + d4 * 32 + seg * 4);
        #pragma unroll
        for (int e = 0; e < NEXP; ++e) {
            float4 w = *(const float4*)&WgL[e * DIM + d4 * 32 + seg * 4];
            lg[e] += v.x * w.x + v.y * w.y + v.z * w.z + v.w * w.w;
        }
    }
    #pragma unroll
    for (int off = 1; off < 8; off <<= 1)
        #pragma unroll
        for (int e = 0; e < NEXP; ++e)
            lg[e] += __shfl_xor(lg[e], off);

    int p0 = 0, p1 = 0, i0 = 0, i1 = 0;
    float g0 = 0.f, g1 = 0.f;
    if (seg == 0) {
        float v0 = -INFINITY, v1 = -INFINITY;
        #pragma unroll
        for (int e = 0; e < NEXP; ++e) {
            float v = lg[e] + bg[e];
            if (v > v0)      { v1 = v0; i1 = i0; v0 = v; i0 = e; }
            else if (v > v1) { v1 = v;  i1 = e; }
        }
        float e1 = expf(v1 - v0);
        g0 = 1.f / (1.f + e1);
        g1 = e1  / (1.f + e1);
        p0 = atomicAdd(&lcnt[i0], 1);
        p1 = atomicAdd(&lcnt[i1], 1);
    }
    __syncthreads();
    if (tid < NEXP) lbase[tid] = atomicAdd(&cnt[tid], lcnt[tid]);
    __syncthreads();
    if (seg == 0) {
        int o0 = lbase[i0] + p0, o1 = lbase[i1] + p1;
        btok[i0 * N_TOK + o0] = t;
        btok[i1 * N_TOK + o1] = t;
        ((int4*)tokmap)[t] = make_int4(i0, o0, i1, o1);
        ((float2*)gmap)[t] = make_float2(g0, g1);
    }
}

// ------------------------------------------ gather x rows into A-fragment order (bf16)
__global__ void gather_kernel(const float* __restrict__ x, const int* __restrict__ cnt,
                              const int* __restrict__ btok, unsigned short* __restrict__ xg) {
    int mt = blockIdx.x, e = blockIdx.y;
    int cntE = cnt[e];
    if (mt * 32 >= cntE) return;
    int tid = threadIdx.x;                 // 256
    int m = tid & 31, kt0 = tid >> 5;      // 32 x 8
    int pos = mt * 32 + m;
    int idx = (pos < cntE) ? pos : cntE - 1;   // clamp pad rows (masked later)
    int tok = btok[e * N_TOK + idx];
    const float* xr = x + (size_t)tok * DIM;
    #pragma unroll
    for (int kk = 0; kk < 3; ++kk) {
        int kt = kt0 + kk * 8;
        #pragma unroll
        for (int kh = 0; kh < 2; ++kh) {
            float4 v0 = *(const float4*)(xr + kt * 16 + kh * 8);
            float4 v1 = *(const float4*)(xr + kt * 16 + kh * 8 + 4);
            unsigned short rr[8];
            rr[0] = f2bf(v0.x); rr[1] = f2bf(v0.y); rr[2] = f2bf(v0.z); rr[3] = f2bf(v0.w);
            rr[4] = f2bf(v1.x); rr[5] = f2bf(v1.y); rr[6] = f2bf(v1.z); rr[7] = f2bf(v1.w);
            *(uint4*)(xg + (size_t)(((e * CAP_MT + mt) * 24 + kt) * 64 + kh * 32 + m) * 8) =
                *(uint4*)rr;
        }
    }
}

// ---------------------------------------------------------------- GEMM1: h = gelu(xg@W1+b1)
// 256 thr / 4 waves, wave-tile 64x64, multi-block/CU (R5: 120 -> 46 us vs fused).
// Staging bases hoisted: waves 0-1 load A tiles, waves 2-3 load B tiles; per wave one
// base pointer + fixed offsets, advancing 2048 shorts per ks. Epilogue: bias + erff
// gelu, transpose via XOR-swizzled stage LDS.
__global__ __launch_bounds__(256, 3) void gemm1_kernel(
        const unsigned short* __restrict__ xg, const unsigned short* __restrict__ w1s,
        const float* __restrict__ b1, const int* __restrict__ cnt,
        unsigned short* __restrict__ h) {
    int L = blockIdx.x;                   // e in low 3 bits: XCD pin
    int e = L & 7;
    int r = L >> 3;
    int nb = r % 12;                      // 128-col slice of HID
    int tb = r / 12;                      // 128-token block
    int cntE = cnt[e];
    if (tb * 128 >= cntE) return;

    __shared__ unsigned short stg[32 * 512];   // 32 KB: A tiles [0..15], B tiles [16..31]

    int tid = threadIdx.x;
    int wave = tid >> 6, lane = tid & 63;
    int m31 = lane & 31, kh = lane >> 5;
    int wm = wave & 1, wn = wave >> 1;    // 64-row half, 64-col half

    f32x16 acc[2][2];
    #pragma unroll
    for (int i = 0; i < 2; ++i)
        #pragma unroll
        for (int j = 0; j < 2; ++j)
            acc[i][j] = (f32x16){0.f,0.f,0.f,0.f,0.f,0.f,0.f,0.f,0.f,0.f,0.f,0.f,0.f,0.f,0.f,0.f};

    const unsigned short* xa = xg  + ((size_t)(e * CAP_MT + tb * 4) * 24) * 512;
    const unsigned short* wb = w1s + ((size_t)(e * 48 + nb * 4) * 24) * 512;

    // hoisted per-wave staging base: waves 0-1 -> A rows (mt = wave*2 + (q>>2)),
    // waves 2-3 -> B cols (nt = (wave-2)*2 + (q>>2)); tile (q&3) of each ks group.
    const unsigned short* sbase = (wave < 2)
        ? xa + ((size_t)(wave * 2) * 24) * 512 + lane * 8
        : wb + ((size_t)((wave - 2) * 2) * 24) * 512 + lane * 8;
    unsigned short* dbase = &stg[wave * 8 * 512];

    for (int ks = 0; ks < 6; ++ks) {            // K = 384 = 6 x BK64
        __syncthreads();                         // stg free
        const unsigned short* sk = sbase + ks * 2048;
        #pragma unroll
        for (int q = 0; q < 8; ++q)
            cp16(sk + (q >> 2) * (24 * 512) + (q & 3) * 512, dbase + q * 512);
        __syncthreads();                         // drain: tiles visible
        #pragma unroll
        for (int kt = 0; kt < 4; ++kt) {
            bf16x8 a0 = *(const bf16x8*)&stg[((wm * 2 + 0) * 4 + kt) * 512 + lane * 8];
            bf16x8 a1 = *(const bf16x8*)&stg[((wm * 2 + 1) * 4 + kt) * 512 + lane * 8];
            bf16x8 b0 = *(const bf16x8*)&stg[(16 + (wn * 2 + 0) * 4 + kt) * 512 + lane * 8];
            bf16x8 b1v = *(const bf16x8*)&stg[(16 + (wn * 2 + 1) * 4 + kt) * 512 + lane * 8];
            acc[0][0] = __builtin_amdgcn_mfma_f32_32x32x16_bf16(a0, b0,  acc[0][0], 0, 0, 0);
            acc[0][1] = __builtin_amdgcn_mfma_f32_32x32x16_bf16(a0, b1v, acc[0][1], 0, 0, 0);
            acc[1][0] = __builtin_amdgcn_mfma_f32_32x32x16_bf16(a1, b0,  acc[1][0], 0, 0, 0);
            acc[1][1] = __builtin_amdgcn_mfma_f32_32x32x16_bf16(a1, b1v, acc[1][1], 0, 0, 0);
        }
    }

    // ---- epilogue: bias + gelu -> wave-private 8 KB LDS region (XOR-swizzled) ----
    __syncthreads();                             // all waves done reading stg
    char* hw = (char*)&stg[wave * 4096];         // 64 rows x 128 B
    float bv0 = b1[e * HID + nb * 128 + wn * 64 + m31];
    float bv1 = b1[e * HID + nb * 128 + wn * 64 + 32 + m31];
    #pragma unroll
    for (int im = 0; im < 2; ++im)
        #pragma unroll
        for (int in = 0; in < 2; ++in) {
            float bv = in ? bv1 : bv0;
            #pragma unroll
            for (int rr = 0; rr < 16; ++rr) {
                int row = im * 32 + (rr & 3) + 8 * (rr >> 2) + 4 * kh;   // local token row
                int col = in * 32 + m31;                                  // local hid col
                unsigned boff = (unsigned)(row * 128 + col * 2) ^ ((row & 7) << 4);
                *(unsigned short*)(hw + boff) = f2bf(gelu_exact(acc[im][in][rr] + bv));
            }
        }
    // wave-private RAW: compiler inserts lgkmcnt. Read back as A-fragment tiles, store.
    #pragma unroll
    for (int mtl = 0; mtl < 2; ++mtl)
        #pragma unroll
        for (int ktl = 0; ktl < 4; ++ktl) {
            int rowl = mtl * 32 + m31;
            int coll = ktl * 16 + kh * 8;
            unsigned boff = (unsigned)(rowl * 128 + coll * 2) ^ ((rowl & 7) << 4);
            uint4 v = *(const uint4*)(hw + boff);
            int mt = tb * 4 + wm * 2 + mtl;           // token tile (32 rows)
            int kt = nb * 8 + wn * 4 + ktl;           // hid tile (16 k)
            *(uint4*)(h + ((size_t)((e * CAP_MT + mt) * 96 + kt)) * 512 + lane * 8) = v;
        }
}

// ---------------------------------------------------------------- GEMM2: yp = h @ W2
// 8 waves (512 thr), wave-tile 64x32, acc 32 regs: at the fixed 432-block grid this
// doubles resident waves/CU (~13 vs ~7) to overlap staging drains — the grid is too
// small for block-level TLP alone. Same 32-tile stage; 4 cp16/wave, hoisted bases.
// Full-K f32 accumulation; epilogue transposes 64x32 per wave via 4 KB LDS region
// (read-back is addr=16*lane linear -> conflict-free, no swizzle needed).
__global__ __launch_bounds__(512, 4) void gemm2_kernel(
        const unsigned short* __restrict__ h, const unsigned short* __restrict__ w2s,
        const int* __restrict__ cnt, unsigned short* __restrict__ yp) {
    int L = blockIdx.x;
    int e = L & 7;
    int r = L >> 3;
    int nb = r % 3;                        // 128-col slice of OUTD
    int tb = r / 3;                        // 128-token block
    int cntE = cnt[e];
    if (tb * 128 >= cntE) return;

    __shared__ unsigned short stg[32 * 512];   // 32 KB: A tiles [0..15], B tiles [16..31]

    int tid = threadIdx.x;
    int wave = tid >> 6, lane = tid & 63;
    int m31 = lane & 31, kh = lane >> 5;
    int wm = wave & 1;                     // 64-row half
    int wn = wave >> 1;                    // 32-col quarter (0..3)

    f32x16 acc[2];
    acc[0] = (f32x16){0.f,0.f,0.f,0.f,0.f,0.f,0.f,0.f,0.f,0.f,0.f,0.f,0.f,0.f,0.f,0.f};
    acc[1] = acc[0];

    const unsigned short* xa = h   + ((size_t)(e * CAP_MT + tb * 4) * 96) * 512;
    const unsigned short* wb = w2s + ((size_t)(e * 12 + nb * 4) * 96) * 512;

    // hoisted: waves 0-3 load A tiles (mt = wave), waves 4-7 load B tiles (nt = wave-4)
    const unsigned short* sbase = (wave < 4)
        ? xa + ((size_t)wave * 96) * 512 + lane * 8
        : wb + ((size_t)(wave - 4) * 96) * 512 + lane * 8;
    unsigned short* dbase = &stg[wave * 4 * 512];

    for (int ks = 0; ks < 24; ++ks) {          // K = 1536 = 24 x BK64
        __syncthreads();
        const unsigned short* sk = sbase + ks * 2048;
        #pragma unroll
        for (int q = 0; q < 4; ++q)
            cp16(sk + q * 512, dbase + q * 512);
        __syncthreads();
        #pragma unroll
        for (int kt = 0; kt < 4; ++kt) {
            bf16x8 b  = *(const bf16x8*)&stg[(16 + wn * 4 + kt) * 512 + lane * 8];
            bf16x8 a0 = *(const bf16x8*)&stg[((wm * 2 + 0) * 4 + kt) * 512 + lane * 8];
            bf16x8 a1 = *(const bf16x8*)&stg[((wm * 2 + 1) * 4 + kt) * 512 + lane * 8];
            acc[0] = __builtin_amdgcn_mfma_f32_32x32x16_bf16(a0, b, acc[0], 0, 0, 0);
            acc[1] = __builtin_amdgcn_mfma_f32_32x32x16_bf16(a1, b, acc[1], 0, 0, 0);
        }
    }

    // ---- epilogue: per-wave 4 KB region, rows [wm*64 .. +64) x cols [wn*32 .. +32) ----
    __syncthreads();                           // all waves done with stage reads
    char* hw = (char*)&stg[wave * 2048];       // 64 rows x 64 B
    #pragma unroll
    for (int s = 0; s < 2; ++s)
        #pragma unroll
        for (int rr = 0; rr < 16; ++rr) {
            int rowl = s * 32 + (rr & 3) + 8 * (rr >> 2) + 4 * kh;   // 0..63
            *(unsigned short*)(hw + rowl * 64 + m31 * 2) = f2bf(acc[s][rr]);
        }
    // read-back: addr = it*1024 + lane*16 (linear, conflict-free); store row-major
    #pragma unroll
    for (int it = 0; it < 4; ++it) {
        int rowl = it * 16 + (lane >> 2);
        int cc   = lane & 3;
        uint4 v = *(const uint4*)(hw + rowl * 64 + cc * 16);
        int pos = tb * 128 + wm * 64 + rowl;
        *(uint4*)(yp + (size_t)(e * CAP_TOK + pos) * OUTD + nb * 128 + wn * 32 + cc * 8) = v;
    }
}

// ----------- reduce: out = sum_k g_k * (yp[e_k][pos_k] + b2[e_k]); single full-K partial
__global__ void reduce_kernel(const unsigned short* __restrict__ yp,
                              const int* __restrict__ tokmap, const float* __restrict__ gmap,
                              const float* __restrict__ b2, float* __restrict__ out) {
    int gid = blockIdx.x * 256 + threadIdx.x;      // N_TOK * 48 threads
    int t = gid / 48, q = gid - t * 48;            // q: 8-col group
    int4   tm = ((const int4*)tokmap)[t];
    float2 g  = ((const float2*)gmap)[t];
    const unsigned short* p0 = yp + ((size_t)(tm.x * CAP_TOK + tm.y)) * OUTD + q * 8;
    const unsigned short* p1 = yp + ((size_t)(tm.z * CAP_TOK + tm.w)) * OUTD + q * 8;
    u16x8 a = __builtin_nontemporal_load((const u16x8*)p0);
    u16x8 b = __builtin_nontemporal_load((const u16x8*)p1);
    const float* c0 = &b2[tm.x * OUTD + q * 8];
    const float* c1 = &b2[tm.z * OUTD + q * 8];
    f32x4 r0, r1;
    #pragma unroll
    for (int j = 0; j < 4; ++j) {
        r0[j] = g.x * (bf2f(a[j]) + c0[j]) + g.y * (bf2f(b[j]) + c1[j]);
        r1[j] = g.x * (bf2f(a[4 + j]) + c0[4 + j]) + g.y * (bf2f(b[4 + j]) + c1[4 + j]);
    }
    float* op = &out[(size_t)t * OUTD + q * 8];
    __builtin_nontemporal_store(r0, (f32x4*)op);
    __builtin_nontemporal_store(r1, (f32x4*)(op + 4));
}

// ---------------------------------------------------------------- launch
extern "C" void kernel_launch(void* const* d_in, const int* in_sizes, int n_in,
                              void* d_out, int out_size, void* d_ws, size_t ws_size,
                              hipStream_t stream) {
    const float* x  = (const float*)d_in[0];
    const float* Wg = (const float*)d_in[1];
    const float* bg = (const float*)d_in[2];
    const float* W1 = (const float*)d_in[3];
    const float* b1 = (const float*)d_in[4];
    const float* W2 = (const float*)d_in[5];
    const float* b2 = (const float*)d_in[6];
    float* out = (float*)d_out;

    char* ws = (char*)d_ws;                                    // all offsets 1KB-aligned
    int*            cnt    = (int*)ws;                         // 32 B
    int*            btok   = (int*)(ws + 1024);                // 256 KB
    int*            tokmap = (int*)(ws + 263168);              // 128 KB
    float*          gmap   = (float*)(ws + 394240);            // 64 KB
    unsigned short* xg     = (unsigned short*)(ws + 459776);   // 13.5 MB (tiles 8x72x24)
    unsigned short* w1s    = (unsigned short*)(ws + 14615552); // 9.44 MB
    unsigned short* w2s    = (unsigned short*)(ws + 24052736); // 9.44 MB
    unsigned short* h      = (unsigned short*)(ws + 33489920); // 56.6 MB (tiles 8x72x96)
    // yp (8 x 2304 x 384 bf16 = 13.5 MB) aliases the xg slot: gemm2 runs strictly after
    // gemm1's last read of xg (same stream), and next iteration's gather fully rewrites
    // the tiles gemm1 reads. Keeps workspace footprint identical.
    unsigned short* yp     = xg;

    // merged W1+W2 swizzle: (589824 + 589824) / 256 = 4608 blocks exactly
    hipLaunchKernelGGL(swizzle_kernel, dim3(4608), dim3(256), 0, stream,
                       W1, W2, w1s, w2s, cnt);
    hipLaunchKernelGGL(router_kernel, dim3(N_TOK / 32), dim3(256), 0, stream,
                       x, Wg, bg, cnt, btok, tokmap, gmap);
    hipLaunchKernelGGL(gather_kernel, dim3(CAP_MT, NEXP), dim3(256), 0, stream,
                       x, cnt, btok, xg);
    hipLaunchKernelGGL(gemm1_kernel, dim3(NEXP * 12 * CAP_TB), dim3(256), 0, stream,
                       xg, w1s, b1, cnt, h);
    hipLaunchKernelGGL(gemm2_kernel, dim3(NEXP * 3 * CAP_TB), dim3(512), 0, stream,
                       h, w2s, cnt, yp);
    hipLaunchKernelGGL(reduce_kernel, dim3(N_TOK * 48 / 256), dim3(256), 0, stream,
                       yp, tokmap, gmap, b2, out);
}

// Round 10
// 180.992 us; speedup vs baseline: 2.3896x; 1.0071x over previous
//
#include <hip/hip_runtime.h>
#include <cmath>

#define N_TOK 8192
#define DIM   384
#define NEXP  8
#define HID   1536
#define OUTD  384
#define CAP_MT 72        // 32-row gather tiles per expert (2304 tokens, mean 2048 + 6 sigma)
#define CAP_TOK 2304
#define CAP_TB 18        // 128-row blocks per expert

typedef __attribute__((ext_vector_type(8)))  __bf16 bf16x8;
typedef __attribute__((ext_vector_type(16))) float  f32x16;
typedef __attribute__((ext_vector_type(4)))  float  f32x4;          // nontemporal builtins
typedef __attribute__((ext_vector_type(8)))  unsigned short u16x8;  // nontemporal bf16 loads

__device__ __forceinline__ unsigned short f2bf(float f) {
    unsigned u = __float_as_uint(f);
    u += 0x7FFF + ((u >> 16) & 1);          // round-to-nearest-even
    return (unsigned short)(u >> 16);
}

__device__ __forceinline__ float bf2f(unsigned short s) {
    return __uint_as_float(((unsigned)s) << 16);
}

// R7 lesson: A&S-polynomial gelu with a (non-fast-math) IEEE divide + __expf is SLOWER
// than libm erff (VALUBusy 43->56%, gemm1 46->51 us). Measured-fast form:
__device__ __forceinline__ float gelu_exact(float x) {
    return 0.5f * x * (1.0f + erff(x * 0.70710678118654752f));
}

// async global->LDS, 16B per lane; LDS dest = wave-uniform tile base (HW adds lane*16)
__device__ __forceinline__ void cp16(const unsigned short* g, unsigned short* l) {
    __builtin_amdgcn_global_load_lds(
        (const __attribute__((address_space(1))) unsigned int*)g,
        (__attribute__((address_space(3))) unsigned int*)l, 16, 0, 0);
}

// ------------------------- merged W1+W2 swizzle: fp32 [e][K][N] -> B-fragment bf16 tiles
// dst[((e*NT + nt)*KT + kt)*64 + l][j] = bf16(src[e][kt*16 + (l>>5)*8 + j][nt*32 + (l&31)])
// T1 = T2 = 589824 threads -> grid 4608x256 exactly. Block 0 zeroes cnt.
__global__ void swizzle_kernel(const float* __restrict__ W1, const float* __restrict__ W2,
                               unsigned short* __restrict__ w1s, unsigned short* __restrict__ w2s,
                               int* __restrict__ cnt) {
    if (blockIdx.x == 0 && threadIdx.x < NEXP) cnt[threadIdx.x] = 0;
    int gid = blockIdx.x * blockDim.x + threadIdx.x;
    const int T1 = NEXP * 48 * 24 * 64;        // 589824 threads for W1
    const int T2 = NEXP * 12 * 96 * 64;        // 589824 threads for W2
    const float* src; unsigned short* dst; int K, N, NT, KT, g;
    if (gid < T1)           { src = W1; dst = w1s; K = DIM; N = HID;  NT = 48; KT = 24; g = gid; }
    else if (gid < T1 + T2) { src = W2; dst = w2s; K = HID; N = OUTD; NT = 12; KT = 96; g = gid - T1; }
    else return;
    int l  = g & 63;
    int kt = (g >> 6) % KT;
    int nt = ((g >> 6) / KT) % NT;
    int e  = g / (64 * KT * NT);
    const float* s = src + ((size_t)e * K + kt * 16 + (l >> 5) * 8) * N + nt * 32 + (l & 31);
    unsigned short r[8];
    #pragma unroll
    for (int j = 0; j < 8; ++j) r[j] = f2bf(s[(size_t)j * N]);
    *(uint4*)(dst + (size_t)g * 8) = *(uint4*)r;
}

// ---------------------------------------------------------------- router
// 256 blocks x 256 thr: 32 tokens/block, 8 threads/token, coalesced 128B chunks;
// Wg staged transposed; __shfl_xor butterfly over seg bits. (R7: verified win.)
__global__ void router_kernel(const float* __restrict__ x, const float* __restrict__ Wg,
                              const float* __restrict__ bg, int* __restrict__ cnt,
                              int* __restrict__ btok, int* __restrict__ tokmap,
                              float* __restrict__ gmap) {
    __shared__ float WgL[NEXP * DIM];          // transposed: WgL[e*DIM + ch]
    __shared__ int lcnt[NEXP];
    __shared__ int lbase[NEXP];
    int tid = threadIdx.x;
    for (int i = tid; i < DIM * NEXP; i += 256) {
        int ch = i >> 3, e = i & 7;            // Wg row-major read = coalesced
        WgL[e * DIM + ch] = Wg[i];
    }
    if (tid < NEXP) lcnt[tid] = 0;
    __syncthreads();

    int tl  = tid >> 3;                        // token-in-block 0..31
    int seg = tid & 7;                         // channel segment 0..7 (lane bits 2:0)
    int t   = blockIdx.x * 32 + tl;

    float lg[NEXP] = {0.f, 0.f, 0.f, 0.f, 0.f, 0.f, 0.f, 0.f};
    const float* xr = x + (size_t)t * DIM;
    #pragma unroll
    for (int d4 = 0; d4 < 12; ++d4) {
        float4 v = *(const float4*)(xr + d4 * 32 + seg * 4);
        #pragma unroll
        for (int e = 0; e < NEXP; ++e) {
            float4 w = *(const float4*)&WgL[e * DIM + d4 * 32 + seg * 4];
            lg[e] += v.x * w.x + v.y * w.y + v.z * w.z + v.w * w.w;
        }
    }
    #pragma unroll
    for (int off = 1; off < 8; off <<= 1)
        #pragma unroll
        for (int e = 0; e < NEXP; ++e)
            lg[e] += __shfl_xor(lg[e], off);

    int p0 = 0, p1 = 0, i0 = 0, i1 = 0;
    float g0 = 0.f, g1 = 0.f;
    if (seg == 0) {
        float v0 = -INFINITY, v1 = -INFINITY;
        #pragma unroll
        for (int e = 0; e < NEXP; ++e) {
            float v = lg[e] + bg[e];
            if (v > v0)      { v1 = v0; i1 = i0; v0 = v; i0 = e; }
            else if (v > v1) { v1 = v;  i1 = e; }
        }
        float e1 = expf(v1 - v0);
        g0 = 1.f / (1.f + e1);
        g1 = e1  / (1.f + e1);
        p0 = atomicAdd(&lcnt[i0], 1);
        p1 = atomicAdd(&lcnt[i1], 1);
    }
    __syncthreads();
    if (tid < NEXP) lbase[tid] = atomicAdd(&cnt[tid], lcnt[tid]);
    __syncthreads();
    if (seg == 0) {
        int o0 = lbase[i0] + p0, o1 = lbase[i1] + p1;
        btok[i0 * N_TOK + o0] = t;
        btok[i1 * N_TOK + o1] = t;
        ((int4*)tokmap)[t] = make_int4(i0, o0, i1, o1);
        ((float2*)gmap)[t] = make_float2(g0, g1);
    }
}

// ------------------------------------------ gather x rows into A-fragment order (bf16)
__global__ void gather_kernel(const float* __restrict__ x, const int* __restrict__ cnt,
                              const int* __restrict__ btok, unsigned short* __restrict__ xg) {
    int mt = blockIdx.x, e = blockIdx.y;
    int cntE = cnt[e];
    if (mt * 32 >= cntE) return;
    int tid = threadIdx.x;                 // 256
    int m = tid & 31, kt0 = tid >> 5;      // 32 x 8
    int pos = mt * 32 + m;
    int idx = (pos < cntE) ? pos : cntE - 1;   // clamp pad rows (masked later)
    int tok = btok[e * N_TOK + idx];
    const float* xr = x + (size_t)tok * DIM;
    #pragma unroll
    for (int kk = 0; kk < 3; ++kk) {
        int kt = kt0 + kk * 8;
        #pragma unroll
        for (int kh = 0; kh < 2; ++kh) {
            float4 v0 = *(const float4*)(xr + kt * 16 + kh * 8);
            float4 v1 = *(const float4*)(xr + kt * 16 + kh * 8 + 4);
            unsigned short rr[8];
            rr[0] = f2bf(v0.x); rr[1] = f2bf(v0.y); rr[2] = f2bf(v0.z); rr[3] = f2bf(v0.w);
            rr[4] = f2bf(v1.x); rr[5] = f2bf(v1.y); rr[6] = f2bf(v1.z); rr[7] = f2bf(v1.w);
            *(uint4*)(xg + (size_t)(((e * CAP_MT + mt) * 24 + kt) * 64 + kh * 32 + m) * 8) =
                *(uint4*)rr;
        }
    }
}

// ---------------------------------------------------------------- GEMM1: h = gelu(xg@W1+b1)
// BK=128: halves the barrier-drain events (per R8 analysis the ~2.5-5k cy drain per
// __syncthreads pair dominates; K=384 -> 3 staging rounds instead of 6). 8 waves
// (512 thr), wave-tile 64x32, acc 32 regs; 64 KB stage (2 blocks/CU, which is what
// we measured anyway at 32 KB). Waves 0-3 stage A (mt=wave, 8 kt-tiles), waves 4-7
// stage B (nt=wave-4). Epilogue: bias + erff gelu, per-wave 64x32 transpose through
// an 80B-pitch region (4-way max bank conflict), store h as A-fragment tiles.
__global__ __launch_bounds__(512, 4) void gemm1_kernel(
        const unsigned short* __restrict__ xg, const unsigned short* __restrict__ w1s,
        const float* __restrict__ b1, const int* __restrict__ cnt,
        unsigned short* __restrict__ h) {
    int L = blockIdx.x;                   // e in low 3 bits: XCD pin
    int e = L & 7;
    int r = L >> 3;
    int nb = r % 12;                      // 128-col slice of HID
    int tb = r / 12;                      // 128-token block
    int cntE = cnt[e];
    if (tb * 128 >= cntE) return;

    __shared__ unsigned short stg[64 * 512];   // 64 KB: A tiles [0..31], B tiles [32..63]

    int tid = threadIdx.x;
    int wave = tid >> 6, lane = tid & 63;
    int m31 = lane & 31, kh = lane >> 5;
    int wm = wave & 1;                    // 64-row half
    int wn = wave >> 1;                   // 32-col quarter (0..3)

    f32x16 acc[2];
    acc[0] = (f32x16){0.f,0.f,0.f,0.f,0.f,0.f,0.f,0.f,0.f,0.f,0.f,0.f,0.f,0.f,0.f,0.f};
    acc[1] = acc[0];

    const unsigned short* xa = xg  + ((size_t)(e * CAP_MT + tb * 4) * 24) * 512;
    const unsigned short* wb = w1s + ((size_t)(e * 48 + nb * 4) * 24) * 512;

    // hoisted per-wave staging base: waves 0-3 -> A (mt = wave), waves 4-7 -> B (nt)
    const unsigned short* sbase = (wave < 4)
        ? xa + ((size_t)wave * 24) * 512 + lane * 8
        : wb + ((size_t)(wave - 4) * 24) * 512 + lane * 8;
    unsigned short* dbase = &stg[wave * 8 * 512];

    for (int ks = 0; ks < 3; ++ks) {            // K = 384 = 3 x BK128
        __syncthreads();                         // stg free
        const unsigned short* sk = sbase + ks * 4096;   // 8 kt-tiles per ks
        #pragma unroll
        for (int q = 0; q < 8; ++q)
            cp16(sk + q * 512, dbase + q * 512);
        __syncthreads();                         // drain: tiles visible
        #pragma unroll
        for (int kt = 0; kt < 8; ++kt) {
            bf16x8 b  = *(const bf16x8*)&stg[(32 + wn * 8 + kt) * 512 + lane * 8];
            bf16x8 a0 = *(const bf16x8*)&stg[((wm * 2 + 0) * 8 + kt) * 512 + lane * 8];
            bf16x8 a1 = *(const bf16x8*)&stg[((wm * 2 + 1) * 8 + kt) * 512 + lane * 8];
            acc[0] = __builtin_amdgcn_mfma_f32_32x32x16_bf16(a0, b, acc[0], 0, 0, 0);
            acc[1] = __builtin_amdgcn_mfma_f32_32x32x16_bf16(a1, b, acc[1], 0, 0, 0);
        }
    }

    // ---- epilogue: bias + gelu -> per-wave 5 KB region (80B pitch), then h tiles ----
    __syncthreads();                             // all waves done reading stg
    char* hw = (char*)stg + wave * 5120;         // 64 rows x 80 B
    float bv = b1[e * HID + nb * 128 + wn * 32 + m31];
    #pragma unroll
    for (int s = 0; s < 2; ++s)
        #pragma unroll
        for (int rr = 0; rr < 16; ++rr) {
            int rowl = s * 32 + (rr & 3) + 8 * (rr >> 2) + 4 * kh;   // 0..63 (token row)
            *(unsigned short*)(hw + rowl * 80 + m31 * 2) = f2bf(gelu_exact(acc[s][rr] + bv));
        }
    // read back as A-fragment tiles (lane l: row = l&31, k = (l>>5)*8 + j), store h.
    // wave-private region: compiler inserts the lgkmcnt for the RAW.
    #pragma unroll
    for (int mtl = 0; mtl < 2; ++mtl)
        #pragma unroll
        for (int ktl = 0; ktl < 2; ++ktl) {
            uint4 v = *(const uint4*)(hw + (mtl * 32 + m31) * 80 + (ktl * 16 + kh * 8) * 2);
            int mt = tb * 4 + wm * 2 + mtl;           // token tile (32 rows)
            int kt = nb * 8 + wn * 2 + ktl;           // hid tile (16 k)
            *(uint4*)(h + ((size_t)((e * CAP_MT + mt) * 96 + kt)) * 512 + lane * 8) = v;
        }
}

// ---------------------------------------------------------------- GEMM2: yp = h @ W2
// BK=128: K = 1536 -> 12 staging rounds instead of 24 (drain-event halving, the same
// lever as gemm1). 8 waves, wave-tile 64x32, 64 KB stage, hoisted bases. Full-K f32
// accumulation; epilogue transposes 64x32 per wave via a 4 KB region.
// R9 bug fixed here: region stride must be wave*4096 BYTES (64 rows x 64 B); the
// (char*)stg + wave*2048 form made adjacent waves' regions overlap -> absmax 0.84.
__global__ __launch_bounds__(512, 4) void gemm2_kernel(
        const unsigned short* __restrict__ h, const unsigned short* __restrict__ w2s,
        const int* __restrict__ cnt, unsigned short* __restrict__ yp) {
    int L = blockIdx.x;
    int e = L & 7;
    int r = L >> 3;
    int nb = r % 3;                        // 128-col slice of OUTD
    int tb = r / 3;                        // 128-token block
    int cntE = cnt[e];
    if (tb * 128 >= cntE) return;

    __shared__ unsigned short stg[64 * 512];   // 64 KB: A tiles [0..31], B tiles [32..63]

    int tid = threadIdx.x;
    int wave = tid >> 6, lane = tid & 63;
    int m31 = lane & 31, kh = lane >> 5;
    int wm = wave & 1;                     // 64-row half
    int wn = wave >> 1;                    // 32-col quarter (0..3)

    f32x16 acc[2];
    acc[0] = (f32x16){0.f,0.f,0.f,0.f,0.f,0.f,0.f,0.f,0.f,0.f,0.f,0.f,0.f,0.f,0.f,0.f};
    acc[1] = acc[0];

    const unsigned short* xa = h   + ((size_t)(e * CAP_MT + tb * 4) * 96) * 512;
    const unsigned short* wb = w2s + ((size_t)(e * 12 + nb * 4) * 96) * 512;

    const unsigned short* sbase = (wave < 4)
        ? xa + ((size_t)wave * 96) * 512 + lane * 8
        : wb + ((size_t)(wave - 4) * 96) * 512 + lane * 8;
    unsigned short* dbase = &stg[wave * 8 * 512];

    for (int ks = 0; ks < 12; ++ks) {          // K = 1536 = 12 x BK128
        __syncthreads();
        const unsigned short* sk = sbase + ks * 4096;
        #pragma unroll
        for (int q = 0; q < 8; ++q)
            cp16(sk + q * 512, dbase + q * 512);
        __syncthreads();
        #pragma unroll
        for (int kt = 0; kt < 8; ++kt) {
            bf16x8 b  = *(const bf16x8*)&stg[(32 + wn * 8 + kt) * 512 + lane * 8];
            bf16x8 a0 = *(const bf16x8*)&stg[((wm * 2 + 0) * 8 + kt) * 512 + lane * 8];
            bf16x8 a1 = *(const bf16x8*)&stg[((wm * 2 + 1) * 8 + kt) * 512 + lane * 8];
            acc[0] = __builtin_amdgcn_mfma_f32_32x32x16_bf16(a0, b, acc[0], 0, 0, 0);
            acc[1] = __builtin_amdgcn_mfma_f32_32x32x16_bf16(a1, b, acc[1], 0, 0, 0);
        }
    }

    // ---- epilogue: per-wave 4 KB region (64 rows x 64 B), rows [wm*64..+64) x cols
    //      [wn*32..+32) ----
    __syncthreads();                           // all waves done with stage reads
    char* hw = (char*)stg + wave * 4096;       // FIXED: 4096-byte stride (was 2048)
    #pragma unroll
    for (int s = 0; s < 2; ++s)
        #pragma unroll
        for (int rr = 0; rr < 16; ++rr) {
            int rowl = s * 32 + (rr & 3) + 8 * (rr >> 2) + 4 * kh;   // 0..63
            *(unsigned short*)(hw + rowl * 64 + m31 * 2) = f2bf(acc[s][rr]);
        }
    // read-back: addr = it*1024 + lane*16 (4-way max); store row-major
    #pragma unroll
    for (int it = 0; it < 4; ++it) {
        int rowl = it * 16 + (lane >> 2);
        int cc   = lane & 3;
        uint4 v = *(const uint4*)(hw + rowl * 64 + cc * 16);
        int pos = tb * 128 + wm * 64 + rowl;
        *(uint4*)(yp + (size_t)(e * CAP_TOK + pos) * OUTD + nb * 128 + wn * 32 + cc * 8) = v;
    }
}

// ----------- reduce: out = sum_k g_k * (yp[e_k][pos_k] + b2[e_k]); single full-K partial
__global__ void reduce_kernel(const unsigned short* __restrict__ yp,
                              const int* __restrict__ tokmap, const float* __restrict__ gmap,
                              const float* __restrict__ b2, float* __restrict__ out) {
    int gid = blockIdx.x * 256 + threadIdx.x;      // N_TOK * 48 threads
    int t = gid / 48, q = gid - t * 48;            // q: 8-col group
    int4   tm = ((const int4*)tokmap)[t];
    float2 g  = ((const float2*)gmap)[t];
    const unsigned short* p0 = yp + ((size_t)(tm.x * CAP_TOK + tm.y)) * OUTD + q * 8;
    const unsigned short* p1 = yp + ((size_t)(tm.z * CAP_TOK + tm.w)) * OUTD + q * 8;
    u16x8 a = __builtin_nontemporal_load((const u16x8*)p0);
    u16x8 b = __builtin_nontemporal_load((const u16x8*)p1);
    const float* c0 = &b2[tm.x * OUTD + q * 8];
    const float* c1 = &b2[tm.z * OUTD + q * 8];
    f32x4 r0, r1;
    #pragma unroll
    for (int j = 0; j < 4; ++j) {
        r0[j] = g.x * (bf2f(a[j]) + c0[j]) + g.y * (bf2f(b[j]) + c1[j]);
        r1[j] = g.x * (bf2f(a[4 + j]) + c0[4 + j]) + g.y * (bf2f(b[4 + j]) + c1[4 + j]);
    }
    float* op = &out[(size_t)t * OUTD + q * 8];
    __builtin_nontemporal_store(r0, (f32x4*)op);
    __builtin_nontemporal_store(r1, (f32x4*)(op + 4));
}

// ---------------------------------------------------------------- launch
extern "C" void kernel_launch(void* const* d_in, const int* in_sizes, int n_in,
                              void* d_out, int out_size, void* d_ws, size_t ws_size,
                              hipStream_t stream) {
    const float* x  = (const float*)d_in[0];
    const float* Wg = (const float*)d_in[1];
    const float* bg = (const float*)d_in[2];
    const float* W1 = (const float*)d_in[3];
    const float* b1 = (const float*)d_in[4];
    const float* W2 = (const float*)d_in[5];
    const float* b2 = (const float*)d_in[6];
    float* out = (float*)d_out;

    char* ws = (char*)d_ws;                                    // all offsets 1KB-aligned
    int*            cnt    = (int*)ws;                         // 32 B
    int*            btok   = (int*)(ws + 1024);                // 256 KB
    int*            tokmap = (int*)(ws + 263168);              // 128 KB
    float*          gmap   = (float*)(ws + 394240);            // 64 KB
    unsigned short* xg     = (unsigned short*)(ws + 459776);   // 13.5 MB (tiles 8x72x24)
    unsigned short* w1s    = (unsigned short*)(ws + 14615552); // 9.44 MB
    unsigned short* w2s    = (unsigned short*)(ws + 24052736); // 9.44 MB
    unsigned short* h      = (unsigned short*)(ws + 33489920); // 56.6 MB (tiles 8x72x96)
    // yp (8 x 2304 x 384 bf16 = 13.5 MB) aliases the xg slot: gemm2 runs strictly after
    // gemm1's last read of xg (same stream), and next iteration's gather fully rewrites
    // the tiles gemm1 reads. Keeps workspace footprint identical.
    unsigned short* yp     = xg;

    // merged W1+W2 swizzle: (589824 + 589824) / 256 = 4608 blocks exactly
    hipLaunchKernelGGL(swizzle_kernel, dim3(4608), dim3(256), 0, stream,
                       W1, W2, w1s, w2s, cnt);
    hipLaunchKernelGGL(router_kernel, dim3(N_TOK / 32), dim3(256), 0, stream,
                       x, Wg, bg, cnt, btok, tokmap, gmap);
    hipLaunchKernelGGL(gather_kernel, dim3(CAP_MT, NEXP), dim3(256), 0, stream,
                       x, cnt, btok, xg);
    hipLaunchKernelGGL(gemm1_kernel, dim3(NEXP * 12 * CAP_TB), dim3(512), 0, stream,
                       xg, w1s, b1, cnt, h);
    hipLaunchKernelGGL(gemm2_kernel, dim3(NEXP * 3 * CAP_TB), dim3(512), 0, stream,
                       h, w2s, cnt, yp);
    hipLaunchKernelGGL(reduce_kernel, dim3(N_TOK * 48 / 256), dim3(256), 0, stream,
                       yp, tokmap, gmap, b2, out);
}